// Round 6
// baseline (322.991 us; speedup 1.0000x reference)
//
#include <hip/hip_runtime.h>
#include <hip/hip_fp16.h>
#include <math.h>

#define C 128
#define HB 2048          // histogram buckets (top 11 bits of ordered float)
#define NS 4096          // candidate capacity (pow2 for bitonic)
#define SHB 128          // score/hist blocks inside k_front

__device__ inline unsigned ord_f32(float f) {
    unsigned u = __float_as_uint(f);
    return u ^ ((u & 0x80000000u) ? 0xFFFFFFFFu : 0x80000000u);
}
__device__ inline float unord_f32(unsigned u) {
    return __uint_as_float(u ^ ((u & 0x80000000u) ? 0x80000000u : 0xFFFFFFFFu));
}
__device__ inline unsigned pack_h2(float a, float b) {
    __half2 h = __floats2half2_rn(a, b);
    return *(unsigned*)&h;
}
__device__ inline unsigned long long enc_w(float w) {
    return (1ULL << 40) | (unsigned long long)(w * 67108864.0f + 0.5f);  // cnt<<40 | fixed26(w)
}

// ---------------------------------------------------------------- front: blocks [0,SHB) scores+hist, rest deg/cnt
__global__ __launch_bounds__(1024) void k_front(const float* __restrict__ X,
                                                const float* __restrict__ p,
                                                float* __restrict__ scores,
                                                int* __restrict__ hist,
                                                const int* __restrict__ ei,
                                                const float* __restrict__ ew,
                                                unsigned long long* __restrict__ pack,
                                                int N, int E) {
    int t = threadIdx.x;
    if (blockIdx.x < SHB) {
        __shared__ int lh[HB];
        for (int i = t; i < HB; i += 1024) lh[i] = 0;
        __syncthreads();
        int gw   = blockIdx.x * 16 + (t >> 6);     // SHB*16 = 2048 waves
        int lane = t & 63;
        for (int r = gw; r < N; r += 2048) {
            const float* xr = X + (size_t)r * C;
            float a = xr[lane] * p[lane] + xr[lane + 64] * p[lane + 64];
            #pragma unroll
            for (int o = 32; o; o >>= 1) a += __shfl_down(a, o);
            if (lane == 0) {
                scores[r] = a;
                atomicAdd(&lh[ord_f32(a) >> 21], 1);
            }
        }
        __syncthreads();
        for (int i = t; i < HB; i += 1024) {
            int v = lh[i];
            if (v) atomicAdd(&hist[i], v);
        }
    } else {
        int e = ((blockIdx.x - SHB) * 1024 + t) * 2;
        if (e + 1 < E) {
            int2 d2   = *(const int2*)(ei + E + e);
            float2 w2 = *(const float2*)(ew + e);
            atomicAdd(&pack[d2.x], enc_w(w2.x));
            atomicAdd(&pack[d2.y], enc_w(w2.y));
        } else if (e < E) {
            atomicAdd(&pack[ei[E + e]], enc_w(ew[e]));
        }
    }
}

// ---------------------------------------------------------------- filter with inline threshold scan
__global__ __launch_bounds__(256) void k_filter(const float* __restrict__ scores,
                                                const int* __restrict__ hist,
                                                int* __restrict__ nc,
                                                unsigned long long* __restrict__ cand, int N) {
    __shared__ int sc[256];
    __shared__ int sT;
    int t = threadIdx.x;
    int loc[8];
    int sum = 0;
    #pragma unroll
    for (int s = 0; s < 8; s++) {
        loc[s] = hist[HB - 1 - (t * 8 + s)];
        sum += loc[s];
    }
    sc[t] = sum;
    __syncthreads();
    for (int off = 1; off < 256; off <<= 1) {
        int v = (t >= off) ? sc[t - off] : 0;
        __syncthreads();
        sc[t] += v;
        __syncthreads();
    }
    int run = sc[t] - sum;
    #pragma unroll
    for (int s = 0; s < 8; s++) {
        int b = HB - 1 - (t * 8 + s);
        int nr = run + loc[s];
        if (run < C && nr >= C) sT = b;
        run = nr;
    }
    __syncthreads();
    int T = sT;
    int i = blockIdx.x * 256 + t;
    if (i < N) {
        unsigned u = ord_f32(scores[i]);
        if ((int)(u >> 21) >= T) {
            int pos = atomicAdd(nc, 1);
            if (pos < NS)
                cand[pos] = ((unsigned long long)u << 32) | (unsigned)(~(unsigned)i);
        }
    }
}

// ---------------------------------------------------------------- adaptive bitonic sort desc, emit top-128
__global__ __launch_bounds__(1024) void k_sel(const unsigned long long* __restrict__ cand,
                                              const int* __restrict__ nc,
                                              const float* __restrict__ p,
                                              int* __restrict__ tidx, float* __restrict__ gate) {
    __shared__ unsigned long long sk[NS];
    __shared__ float red[16];
    __shared__ float s_pn;
    int t = threadIdx.x;
    int M = *nc; if (M > NS) M = NS;
    int S = 256; while (S < M) S <<= 1;          // sort size: pow2 >= max(M,256)
    for (int i = t; i < S; i += 1024) sk[i] = (i < M) ? cand[i] : 0ULL;
    float pv = 0.f;
    if (t < C) { float x = p[t]; pv = x * x; }
    #pragma unroll
    for (int o = 32; o; o >>= 1) pv += __shfl_down(pv, o);
    if ((t & 63) == 0) red[t >> 6] = pv;
    __syncthreads();
    if (t == 0) {
        float s = 0.f;
        for (int i = 0; i < 16; i++) s += red[i];
        s_pn = sqrtf(s);
    }
    for (int k = 2; k <= S; k <<= 1) {
        for (int j = k >> 1; j > 0; j >>= 1) {
            __syncthreads();
            for (int idx = t; idx < S; idx += 1024) {
                int l = idx ^ j;
                if (l > idx) {
                    unsigned long long a = sk[idx], b = sk[l];
                    bool desc = (idx & k) == 0;
                    if (desc ? (a < b) : (a > b)) { sk[idx] = b; sk[l] = a; }
                }
            }
        }
    }
    __syncthreads();
    if (t < C) {
        unsigned long long g = sk[t];
        tidx[t] = (int)(~(unsigned)(g & 0xFFFFFFFFull));
        gate[t] = tanhf(unord_f32((unsigned)(g >> 32)) / s_pn);
    }
}

// ---------------------------------------------------------------- scan A: per-block scan of counts + dinv
__global__ __launch_bounds__(256) void k_scan1(const unsigned long long* __restrict__ pack,
                                               int* __restrict__ pref, int* __restrict__ bsum,
                                               float* __restrict__ dinv, int N) {
    __shared__ int sc[256];
    int t = threadIdx.x;
    int i = blockIdx.x * 256 + t;
    int v = 0;
    if (i < N) {
        unsigned long long pk = pack[i];
        v = (int)(pk >> 40);
        float deg = 1.0f + (float)(pk & 0xFFFFFFFFFFULL) * (1.0f / 67108864.0f);
        dinv[i] = rsqrtf(deg);
    }
    sc[t] = v;
    __syncthreads();
    for (int off = 1; off < 256; off <<= 1) {
        int u = (t >= off) ? sc[t - off] : 0;
        __syncthreads();
        sc[t] += u;
        __syncthreads();
    }
    if (i < N) pref[i] = sc[t] - v;
    if (t == 255) bsum[blockIdx.x] = sc[255];
}

// ---------------------------------------------------------------- scan B+C merged: each block sums its bsum prefix
__global__ __launch_bounds__(256) void k_scan3(const int* __restrict__ pref, const int* __restrict__ bsum,
                                               int* __restrict__ offs, int* __restrict__ cursor,
                                               int N, int E, int NB) {
    __shared__ int red[4];
    int t = threadIdx.x, bid = blockIdx.x;
    int v = (t < NB && t < bid) ? bsum[t] : 0;
    #pragma unroll
    for (int o = 32; o; o >>= 1) v += __shfl_down(v, o);
    if ((t & 63) == 0) red[t >> 6] = v;
    __syncthreads();
    int base = red[0] + red[1] + red[2] + red[3];
    int i = bid * 256 + t;
    if (i < N) {
        int o = base + pref[i];
        offs[i] = o;
        cursor[i] = o;
    }
    if (i == 0) offs[N] = E;
}

// ---------------------------------------------------------------- GRU step (X_tilde folded in) -> W_new^T
__global__ __launch_bounds__(256) void k_gru(const float* __restrict__ X,
                                             const int* __restrict__ tidx,
                                             const float* __restrict__ gate,
                                             const float* __restrict__ Wc,
                                             const float* __restrict__ W_ih, const float* __restrict__ W_hh,
                                             const float* __restrict__ b_ih, const float* __restrict__ b_hh,
                                             float* __restrict__ wnewT) {
    int t = threadIdx.x;
    int i = t & 127;
    int j = blockIdx.x * 2 + (t >> 7);
    int src = tidx[i];
    float g = gate[i];
    const float4* xr   = (const float4*)(X + (size_t)src * C);
    const float4* hr   = (const float4*)(Wc + (size_t)i * C);
    const float4* wri  = (const float4*)(W_ih + (size_t)j * C);
    const float4* wzi  = (const float4*)(W_ih + (size_t)(C + j) * C);
    const float4* wni  = (const float4*)(W_ih + (size_t)(2 * C + j) * C);
    const float4* wrh  = (const float4*)(W_hh + (size_t)j * C);
    const float4* wzh  = (const float4*)(W_hh + (size_t)(C + j) * C);
    const float4* wnh  = (const float4*)(W_hh + (size_t)(2 * C + j) * C);
    float gir = 0, giz = 0, gin = 0, ghr = 0, ghz = 0, ghn = 0;
    #pragma unroll 8
    for (int k4 = 0; k4 < C / 4; k4++) {
        float4 x = xr[k4], h = hr[k4], a;
        a = wri[k4]; gir += x.x * a.x + x.y * a.y + x.z * a.z + x.w * a.w;
        a = wzi[k4]; giz += x.x * a.x + x.y * a.y + x.z * a.z + x.w * a.w;
        a = wni[k4]; gin += x.x * a.x + x.y * a.y + x.z * a.z + x.w * a.w;
        a = wrh[k4]; ghr += h.x * a.x + h.y * a.y + h.z * a.z + h.w * a.w;
        a = wzh[k4]; ghz += h.x * a.x + h.y * a.y + h.z * a.z + h.w * a.w;
        a = wnh[k4]; ghn += h.x * a.x + h.y * a.y + h.z * a.z + h.w * a.w;
    }
    gir = g * gir + b_ih[j];         ghr += b_hh[j];
    giz = g * giz + b_ih[C + j];     ghz += b_hh[C + j];
    gin = g * gin + b_ih[2 * C + j]; ghn += b_hh[2 * C + j];
    float r = 1.f / (1.f + expf(-(gir + ghr)));
    float z = 1.f / (1.f + expf(-(giz + ghz)));
    float n = tanhf(gin + r * ghn);
    float wn = (1.f - z) * n + z * Wc[(size_t)i * C + j];
    wnewT[(size_t)j * C + i] = wn;
}

// ---------------------------------------------------------------- edge scatter into CSR order (1 edge/thread)
__global__ __launch_bounds__(256) void k_scatter(const int* __restrict__ ei, const float* __restrict__ ew,
                                                 const float* __restrict__ dinv, int* __restrict__ cursor,
                                                 unsigned long long* __restrict__ epack, int E) {
    int e = blockIdx.x * 256 + threadIdx.x;
    if (e < E) {
        int s = ei[e], d = ei[E + e];
        float nm = dinv[s] * ew[e] * dinv[d];
        int pos = atomicAdd(&cursor[d], 1);
        unsigned long long pk = ((unsigned long long)__float_as_uint(nm) << 32) | (unsigned)s;
        __builtin_nontemporal_store(pk, &epack[pos]);
    }
}

// ---------------------------------------------------------------- Xw = X @ W_new^T, stored fp16 (half2-packed)
__global__ __launch_bounds__(256) void k_xw(const float* __restrict__ X,
                                            const float* __restrict__ wnewT,
                                            unsigned* __restrict__ xwh, int N) {
    __shared__ float Wt[C * C];
    int t = threadIdx.x;
    for (int e = t; e < C * C; e += 256) Wt[e] = wnewT[e];
    __syncthreads();

    int r0 = blockIdx.x * 128;
    int r1 = r0 + (t & 63);
    int r2 = r1 + 64;
    int c0 = (t >> 6) * 32;
    const float4* xr1 = (const float4*)(X + (size_t)(r1 < N ? r1 : N - 1) * C);
    const float4* xr2 = (const float4*)(X + (size_t)(r2 < N ? r2 : N - 1) * C);
    float acc1[32], acc2[32];
    #pragma unroll
    for (int c = 0; c < 32; c++) { acc1[c] = 0.f; acc2[c] = 0.f; }

    for (int k4 = 0; k4 < C / 4; k4++) {
        float4 xa = xr1[k4], xb = xr2[k4];
        #pragma unroll
        for (int kk = 0; kk < 4; kk++) {
            float x1 = ((const float*)&xa)[kk];
            float x2 = ((const float*)&xb)[kk];
            const float* wrow = &Wt[(k4 * 4 + kk) * C + c0];
            #pragma unroll
            for (int cc = 0; cc < 32; cc += 4) {
                float4 wv = *(const float4*)(wrow + cc);
                acc1[cc + 0] += x1 * wv.x; acc1[cc + 1] += x1 * wv.y;
                acc1[cc + 2] += x1 * wv.z; acc1[cc + 3] += x1 * wv.w;
                acc2[cc + 0] += x2 * wv.x; acc2[cc + 1] += x2 * wv.y;
                acc2[cc + 2] += x2 * wv.z; acc2[cc + 3] += x2 * wv.w;
            }
        }
    }
    if (r1 < N) {
        unsigned* orow = xwh + (size_t)r1 * 64 + (c0 >> 1);
        #pragma unroll
        for (int cc = 0; cc < 32; cc += 8) {
            uint4 u;
            u.x = pack_h2(acc1[cc + 0], acc1[cc + 1]);
            u.y = pack_h2(acc1[cc + 2], acc1[cc + 3]);
            u.z = pack_h2(acc1[cc + 4], acc1[cc + 5]);
            u.w = pack_h2(acc1[cc + 6], acc1[cc + 7]);
            *(uint4*)(orow + (cc >> 1)) = u;
        }
    }
    if (r2 < N) {
        unsigned* orow = xwh + (size_t)r2 * 64 + (c0 >> 1);
        #pragma unroll
        for (int cc = 0; cc < 32; cc += 8) {
            uint4 u;
            u.x = pack_h2(acc2[cc + 0], acc2[cc + 1]);
            u.y = pack_h2(acc2[cc + 2], acc2[cc + 3]);
            u.z = pack_h2(acc2[cc + 4], acc2[cc + 5]);
            u.w = pack_h2(acc2[cc + 6], acc2[cc + 7]);
            *(uint4*)(orow + (cc >> 1)) = u;
        }
    }
}

// ---------------------------------------------------------------- gather: 2 waves/node (even/odd edges), LDS combine
__global__ __launch_bounds__(256) void k_gather(const unsigned* __restrict__ xwh,
                                                const int* __restrict__ offs,
                                                const unsigned long long* __restrict__ epack,
                                                const float* __restrict__ dinv,
                                                const float* __restrict__ b_conv,
                                                float* __restrict__ out, int N) {
    __shared__ float2 sacc[2][64];
    int t = threadIdx.x;
    int wv = t >> 6;            // 0..3
    int slot = wv >> 1;         // node slot 0..1
    int sub = wv & 1;           // 0: even edges (+self), 1: odd edges
    int lane = t & 63;
    int v = blockIdx.x * 2 + slot;

    float acc0 = 0.f, acc1 = 0.f;
    int e0 = 0, e1 = 0;
    if (v < N) {
        e0 = offs[v];
        e1 = offs[v + 1];
        if (sub == 0) {
            float dv = dinv[v];
            unsigned uv = xwh[(size_t)v * 64 + lane];
            __half2 hv = *(__half2*)&uv;
            acc0 = dv * dv * __low2float(hv);
            acc1 = dv * dv * __high2float(hv);
        }
    }
    int e = e0 + sub;
    for (; e + 6 < e1; e += 8) {
        unsigned long long p0 = __builtin_nontemporal_load(&epack[e + 0]);
        unsigned long long p1 = __builtin_nontemporal_load(&epack[e + 2]);
        unsigned long long p2 = __builtin_nontemporal_load(&epack[e + 4]);
        unsigned long long p3 = __builtin_nontemporal_load(&epack[e + 6]);
        unsigned u0 = xwh[(size_t)(unsigned)(p0 & 0xFFFFFFFFull) * 64 + lane];
        unsigned u1 = xwh[(size_t)(unsigned)(p1 & 0xFFFFFFFFull) * 64 + lane];
        unsigned u2 = xwh[(size_t)(unsigned)(p2 & 0xFFFFFFFFull) * 64 + lane];
        unsigned u3 = xwh[(size_t)(unsigned)(p3 & 0xFFFFFFFFull) * 64 + lane];
        float n0 = __uint_as_float((unsigned)(p0 >> 32));
        float n1 = __uint_as_float((unsigned)(p1 >> 32));
        float n2 = __uint_as_float((unsigned)(p2 >> 32));
        float n3 = __uint_as_float((unsigned)(p3 >> 32));
        __half2 h0 = *(__half2*)&u0, h1 = *(__half2*)&u1;
        __half2 h2 = *(__half2*)&u2, h3 = *(__half2*)&u3;
        acc0 += n0 * __low2float(h0) + n1 * __low2float(h1)
              + n2 * __low2float(h2) + n3 * __low2float(h3);
        acc1 += n0 * __high2float(h0) + n1 * __high2float(h1)
              + n2 * __high2float(h2) + n3 * __high2float(h3);
    }
    for (; e < e1; e += 2) {
        unsigned long long pA = __builtin_nontemporal_load(&epack[e]);
        unsigned uA = xwh[(size_t)(unsigned)(pA & 0xFFFFFFFFull) * 64 + lane];
        float nA = __uint_as_float((unsigned)(pA >> 32));
        __half2 hA = *(__half2*)&uA;
        acc0 += nA * __low2float(hA);
        acc1 += nA * __high2float(hA);
    }
    if (sub == 1) sacc[slot][lane] = make_float2(acc0, acc1);
    __syncthreads();
    if (sub == 0 && v < N) {
        float2 o = sacc[slot][lane];
        const float2* b2 = (const float2*)b_conv;
        float2 bb = b2[lane];
        float r0 = acc0 + o.x + bb.x;
        float r1 = acc1 + o.y + bb.y;
        unsigned long long ov = ((unsigned long long)__float_as_uint(r1) << 32)
                              |  (unsigned long long)__float_as_uint(r0);
        __builtin_nontemporal_store(ov, (unsigned long long*)(out + (size_t)v * C) + lane);
    }
}

// ---------------------------------------------------------------- launcher
extern "C" void kernel_launch(void* const* d_in, const int* in_sizes, int n_in,
                              void* d_out, int out_size, void* d_ws, size_t ws_size,
                              hipStream_t stream) {
    const float* X      = (const float*)d_in[0];
    const float* ew     = (const float*)d_in[1];
    const float* p      = (const float*)d_in[2];
    const float* W_ih   = (const float*)d_in[3];
    const float* W_hh   = (const float*)d_in[4];
    const float* b_ih   = (const float*)d_in[5];
    const float* b_hh   = (const float*)d_in[6];
    const float* W_conv = (const float*)d_in[7];
    const float* b_conv = (const float*)d_in[8];
    const int*   ei     = (const int*)d_in[9];
    const int N = in_sizes[0] / C;
    const int E = in_sizes[1];
    float* out = (float*)d_out;
    const int NB = (N + 255) / 256;

    char* w = (char*)d_ws;
    auto alloc = [&](size_t bytes) -> void* {
        void* r = (void*)w;
        w += (bytes + 255) & ~(size_t)255;
        return r;
    };
    // zero-init region: pack + hist + nc (single memset)
    unsigned long long* pack = (unsigned long long*)alloc((size_t)N * 8);
    int*   hist   = (int*)alloc(HB * 4);
    int*   nc     = (int*)alloc(256);
    size_t zbytes = (size_t)(w - (char*)d_ws);
    float* scores = (float*)alloc((size_t)N * 4);
    float* dinv   = (float*)alloc((size_t)N * 4);
    int*   offs   = (int*)alloc((size_t)(N + 1) * 4);
    int*   cursor = (int*)alloc((size_t)N * 4);
    int*   pref   = (int*)alloc((size_t)N * 4);
    int*   bsum   = (int*)alloc((size_t)NB * 4);
    unsigned long long* cand = (unsigned long long*)alloc((size_t)NS * 8);
    int*   tidx   = (int*)alloc(C * 4);
    float* gate   = (float*)alloc(C * 4);
    float* wnewT  = (float*)alloc((size_t)C * C * 4);
    unsigned long long* epack = (unsigned long long*)alloc((size_t)E * 8);
    unsigned* xwh = (unsigned*)alloc((size_t)N * 64 * 4);

    hipMemsetAsync(d_ws, 0, zbytes, stream);
    int edgeBlocks = (E / 2 + 1023) / 1024;
    k_front<<<SHB + edgeBlocks, 1024, 0, stream>>>(X, p, scores, hist, ei, ew, pack, N, E);
    k_filter<<<NB, 256, 0, stream>>>(scores, hist, nc, cand, N);
    k_sel<<<1, 1024, 0, stream>>>(cand, nc, p, tidx, gate);
    k_gru<<<C / 2, 256, 0, stream>>>(X, tidx, gate, W_conv, W_ih, W_hh, b_ih, b_hh, wnewT);
    k_scan1<<<NB, 256, 0, stream>>>(pack, pref, bsum, dinv, N);
    k_scan3<<<NB, 256, 0, stream>>>(pref, bsum, offs, cursor, N, E, NB);
    k_scatter<<<(E + 255) / 256, 256, 0, stream>>>(ei, ew, dinv, cursor, epack, E);
    k_xw<<<(N + 127) / 128, 256, 0, stream>>>(X, wnewT, xwh, N);
    k_gather<<<(N + 1) / 2, 256, 0, stream>>>(xwh, offs, epack, dinv, b_conv, out, N);
}

// Round 7
// 297.639 us; speedup vs baseline: 1.0852x; 1.0852x over previous
//
#include <hip/hip_runtime.h>
#include <hip/hip_fp16.h>
#include <math.h>

#define C 128
#define HB 2048          // histogram buckets (top 11 bits of ordered float)
#define NS 4096          // candidate capacity (pow2 for bitonic)
#define SHB 128          // score/hist blocks inside k_front

typedef __attribute__((ext_vector_type(8))) short bf16x8;
typedef __attribute__((ext_vector_type(4))) float f32x4;

__device__ inline unsigned ord_f32(float f) {
    unsigned u = __float_as_uint(f);
    return u ^ ((u & 0x80000000u) ? 0xFFFFFFFFu : 0x80000000u);
}
__device__ inline float unord_f32(unsigned u) {
    return __uint_as_float(u ^ ((u & 0x80000000u) ? 0x80000000u : 0xFFFFFFFFu));
}
__device__ inline unsigned pack_h2(float a, float b) {
    __half2 h = __floats2half2_rn(a, b);
    return *(unsigned*)&h;
}
__device__ inline unsigned long long enc_w(float w) {
    return (1ULL << 40) | (unsigned long long)(w * 67108864.0f + 0.5f);  // cnt<<40 | fixed26(w)
}
__device__ inline short f2bf(float f) {        // RNE float -> bf16 bits
    unsigned u = __float_as_uint(f);
    return (short)((u + 0x7FFFu + ((u >> 16) & 1u)) >> 16);
}
__device__ inline float bf2f(short s) {
    return __uint_as_float(((unsigned)(unsigned short)s) << 16);
}

// ---------------------------------------------------------------- front: blocks [0,SHB) scores+hist, rest deg/cnt
__global__ __launch_bounds__(1024) void k_front(const float* __restrict__ X,
                                                const float* __restrict__ p,
                                                float* __restrict__ scores,
                                                int* __restrict__ hist,
                                                const int* __restrict__ ei,
                                                const float* __restrict__ ew,
                                                unsigned long long* __restrict__ pack,
                                                int N, int E) {
    int t = threadIdx.x;
    if (blockIdx.x < SHB) {
        __shared__ int lh[HB];
        for (int i = t; i < HB; i += 1024) lh[i] = 0;
        __syncthreads();
        int gw   = blockIdx.x * 16 + (t >> 6);     // SHB*16 = 2048 waves
        int lane = t & 63;
        for (int r = gw; r < N; r += 2048) {
            const float* xr = X + (size_t)r * C;
            float a = xr[lane] * p[lane] + xr[lane + 64] * p[lane + 64];
            #pragma unroll
            for (int o = 32; o; o >>= 1) a += __shfl_down(a, o);
            if (lane == 0) {
                scores[r] = a;
                atomicAdd(&lh[ord_f32(a) >> 21], 1);
            }
        }
        __syncthreads();
        for (int i = t; i < HB; i += 1024) {
            int v = lh[i];
            if (v) atomicAdd(&hist[i], v);
        }
    } else {
        int e = ((blockIdx.x - SHB) * 1024 + t) * 2;
        if (e + 1 < E) {
            int2 d2   = *(const int2*)(ei + E + e);
            float2 w2 = *(const float2*)(ew + e);
            atomicAdd(&pack[d2.x], enc_w(w2.x));
            atomicAdd(&pack[d2.y], enc_w(w2.y));
        } else if (e < E) {
            atomicAdd(&pack[ei[E + e]], enc_w(ew[e]));
        }
    }
}

// ---------------------------------------------------------------- filter with inline threshold scan
__global__ __launch_bounds__(256) void k_filter(const float* __restrict__ scores,
                                                const int* __restrict__ hist,
                                                int* __restrict__ nc,
                                                unsigned long long* __restrict__ cand, int N) {
    __shared__ int sc[256];
    __shared__ int sT;
    int t = threadIdx.x;
    int loc[8];
    int sum = 0;
    #pragma unroll
    for (int s = 0; s < 8; s++) {
        loc[s] = hist[HB - 1 - (t * 8 + s)];
        sum += loc[s];
    }
    sc[t] = sum;
    __syncthreads();
    for (int off = 1; off < 256; off <<= 1) {
        int v = (t >= off) ? sc[t - off] : 0;
        __syncthreads();
        sc[t] += v;
        __syncthreads();
    }
    int run = sc[t] - sum;
    #pragma unroll
    for (int s = 0; s < 8; s++) {
        int b = HB - 1 - (t * 8 + s);
        int nr = run + loc[s];
        if (run < C && nr >= C) sT = b;
        run = nr;
    }
    __syncthreads();
    int T = sT;
    int i = blockIdx.x * 256 + t;
    if (i < N) {
        unsigned u = ord_f32(scores[i]);
        if ((int)(u >> 21) >= T) {
            int pos = atomicAdd(nc, 1);
            if (pos < NS)
                cand[pos] = ((unsigned long long)u << 32) | (unsigned)(~(unsigned)i);
        }
    }
}

// ---------------------------------------------------------------- adaptive bitonic sort desc, emit top-128
__global__ __launch_bounds__(1024) void k_sel(const unsigned long long* __restrict__ cand,
                                              const int* __restrict__ nc,
                                              const float* __restrict__ p,
                                              int* __restrict__ tidx, float* __restrict__ gate) {
    __shared__ unsigned long long sk[NS];
    __shared__ float red[16];
    __shared__ float s_pn;
    int t = threadIdx.x;
    int M = *nc; if (M > NS) M = NS;
    int S = 256; while (S < M) S <<= 1;          // sort size: pow2 >= max(M,256)
    for (int i = t; i < S; i += 1024) sk[i] = (i < M) ? cand[i] : 0ULL;
    float pv = 0.f;
    if (t < C) { float x = p[t]; pv = x * x; }
    #pragma unroll
    for (int o = 32; o; o >>= 1) pv += __shfl_down(pv, o);
    if ((t & 63) == 0) red[t >> 6] = pv;
    __syncthreads();
    if (t == 0) {
        float s = 0.f;
        for (int i = 0; i < 16; i++) s += red[i];
        s_pn = sqrtf(s);
    }
    for (int k = 2; k <= S; k <<= 1) {
        for (int j = k >> 1; j > 0; j >>= 1) {
            __syncthreads();
            for (int idx = t; idx < S; idx += 1024) {
                int l = idx ^ j;
                if (l > idx) {
                    unsigned long long a = sk[idx], b = sk[l];
                    bool desc = (idx & k) == 0;
                    if (desc ? (a < b) : (a > b)) { sk[idx] = b; sk[l] = a; }
                }
            }
        }
    }
    __syncthreads();
    if (t < C) {
        unsigned long long g = sk[t];
        tidx[t] = (int)(~(unsigned)(g & 0xFFFFFFFFull));
        gate[t] = tanhf(unord_f32((unsigned)(g >> 32)) / s_pn);
    }
}

// ---------------------------------------------------------------- scan A: per-block scan of counts + dinv
__global__ __launch_bounds__(256) void k_scan1(const unsigned long long* __restrict__ pack,
                                               int* __restrict__ pref, int* __restrict__ bsum,
                                               float* __restrict__ dinv, int N) {
    __shared__ int sc[256];
    int t = threadIdx.x;
    int i = blockIdx.x * 256 + t;
    int v = 0;
    if (i < N) {
        unsigned long long pk = pack[i];
        v = (int)(pk >> 40);
        float deg = 1.0f + (float)(pk & 0xFFFFFFFFFFULL) * (1.0f / 67108864.0f);
        dinv[i] = rsqrtf(deg);
    }
    sc[t] = v;
    __syncthreads();
    for (int off = 1; off < 256; off <<= 1) {
        int u = (t >= off) ? sc[t - off] : 0;
        __syncthreads();
        sc[t] += u;
        __syncthreads();
    }
    if (i < N) pref[i] = sc[t] - v;
    if (t == 255) bsum[blockIdx.x] = sc[255];
}

// ---------------------------------------------------------------- scan B+C merged: each block sums its bsum prefix
__global__ __launch_bounds__(256) void k_scan3(const int* __restrict__ pref, const int* __restrict__ bsum,
                                               int* __restrict__ offs, int* __restrict__ cursor,
                                               int N, int E, int NB) {
    __shared__ int red[4];
    int t = threadIdx.x, bid = blockIdx.x;
    int v = (t < NB && t < bid) ? bsum[t] : 0;
    #pragma unroll
    for (int o = 32; o; o >>= 1) v += __shfl_down(v, o);
    if ((t & 63) == 0) red[t >> 6] = v;
    __syncthreads();
    int base = red[0] + red[1] + red[2] + red[3];
    int i = bid * 256 + t;
    if (i < N) {
        int o = base + pref[i];
        offs[i] = o;
        cursor[i] = o;
    }
    if (i == 0) offs[N] = E;
}

// ---------------------------------------------------------------- GRU step (X_tilde folded in) -> W_new^T
__global__ __launch_bounds__(256) void k_gru(const float* __restrict__ X,
                                             const int* __restrict__ tidx,
                                             const float* __restrict__ gate,
                                             const float* __restrict__ Wc,
                                             const float* __restrict__ W_ih, const float* __restrict__ W_hh,
                                             const float* __restrict__ b_ih, const float* __restrict__ b_hh,
                                             float* __restrict__ wnewT) {
    int t = threadIdx.x;
    int i = t & 127;
    int j = blockIdx.x * 2 + (t >> 7);
    int src = tidx[i];
    float g = gate[i];
    const float4* xr   = (const float4*)(X + (size_t)src * C);
    const float4* hr   = (const float4*)(Wc + (size_t)i * C);
    const float4* wri  = (const float4*)(W_ih + (size_t)j * C);
    const float4* wzi  = (const float4*)(W_ih + (size_t)(C + j) * C);
    const float4* wni  = (const float4*)(W_ih + (size_t)(2 * C + j) * C);
    const float4* wrh  = (const float4*)(W_hh + (size_t)j * C);
    const float4* wzh  = (const float4*)(W_hh + (size_t)(C + j) * C);
    const float4* wnh  = (const float4*)(W_hh + (size_t)(2 * C + j) * C);
    float gir = 0, giz = 0, gin = 0, ghr = 0, ghz = 0, ghn = 0;
    #pragma unroll 8
    for (int k4 = 0; k4 < C / 4; k4++) {
        float4 x = xr[k4], h = hr[k4], a;
        a = wri[k4]; gir += x.x * a.x + x.y * a.y + x.z * a.z + x.w * a.w;
        a = wzi[k4]; giz += x.x * a.x + x.y * a.y + x.z * a.z + x.w * a.w;
        a = wni[k4]; gin += x.x * a.x + x.y * a.y + x.z * a.z + x.w * a.w;
        a = wrh[k4]; ghr += h.x * a.x + h.y * a.y + h.z * a.z + h.w * a.w;
        a = wzh[k4]; ghz += h.x * a.x + h.y * a.y + h.z * a.z + h.w * a.w;
        a = wnh[k4]; ghn += h.x * a.x + h.y * a.y + h.z * a.z + h.w * a.w;
    }
    gir = g * gir + b_ih[j];         ghr += b_hh[j];
    giz = g * giz + b_ih[C + j];     ghz += b_hh[C + j];
    gin = g * gin + b_ih[2 * C + j]; ghn += b_hh[2 * C + j];
    float r = 1.f / (1.f + expf(-(gir + ghr)));
    float z = 1.f / (1.f + expf(-(giz + ghz)));
    float n = tanhf(gin + r * ghn);
    float wn = (1.f - z) * n + z * Wc[(size_t)i * C + j];
    wnewT[(size_t)j * C + i] = wn;
}

// ---------------------------------------------------------------- edge scatter into CSR order (1 edge/thread)
__global__ __launch_bounds__(256) void k_scatter(const int* __restrict__ ei, const float* __restrict__ ew,
                                                 const float* __restrict__ dinv, int* __restrict__ cursor,
                                                 unsigned long long* __restrict__ epack, int E) {
    int e = blockIdx.x * 256 + threadIdx.x;
    if (e < E) {
        int s = ei[e], d = ei[E + e];
        float nm = dinv[s] * ew[e] * dinv[d];
        int pos = atomicAdd(&cursor[d], 1);
        unsigned long long pk = ((unsigned long long)__float_as_uint(nm) << 32) | (unsigned)s;
        __builtin_nontemporal_store(pk, &epack[pos]);
    }
}

// ---------------------------------------------------------------- Xw = X @ W_new^T via MFMA (split-bf16, ~fp32 acc)
// Block: 128 rows, 4 waves x (32 rows x 128 cols). B (W^T as [c][k]) in LDS,
// hi+lo bf16 split, XOR-octet swizzle: elem (c,k) at c*128 + (k ^ ((c&15)<<3))
// -> 16 lanes hit 8 bank-groups 2-way (free, m136). A frags straight from X.
__global__ __launch_bounds__(256) void k_xw(const float* __restrict__ X,
                                            const float* __restrict__ wnewT,
                                            unsigned* __restrict__ xwh, int N) {
    __shared__ short Bh[C * C];
    __shared__ short Bl[C * C];
    int t = threadIdx.x;
    for (int idx = t; idx < C * C; idx += 256) {
        int k = idx >> 7, c = idx & 127;       // wnewT[k*C+c] = W_new[c][k]
        float wv = wnewT[idx];
        short hi = f2bf(wv);
        float lo = wv - bf2f(hi);
        int pos = c * C + (k ^ ((c & 15) << 3));
        Bh[pos] = hi;
        Bl[pos] = f2bf(lo);
    }
    __syncthreads();

    int wave = t >> 6, lane = t & 63;
    int ln = lane & 15, quad = lane >> 4;
    int r0 = blockIdx.x * 128 + wave * 32;

    f32x4 acc[2][8];
    #pragma unroll
    for (int mt = 0; mt < 2; mt++)
        #pragma unroll
        for (int ct = 0; ct < 8; ct++) { acc[mt][ct][0] = 0.f; acc[mt][ct][1] = 0.f; acc[mt][ct][2] = 0.f; acc[mt][ct][3] = 0.f; }

    int row0 = r0 + ln;       if (row0 >= N) row0 = N - 1;
    int row1 = r0 + 16 + ln;  if (row1 >= N) row1 = N - 1;
    const float* xr0 = X + (size_t)row0 * C + quad * 8;
    const float* xr1 = X + (size_t)row1 * C + quad * 8;

    for (int ks = 0; ks < 4; ks++) {
        float a0[8], a1[8];
        *(float4*)&a0[0] = *(const float4*)(xr0 + ks * 32);
        *(float4*)&a0[4] = *(const float4*)(xr0 + ks * 32 + 4);
        *(float4*)&a1[0] = *(const float4*)(xr1 + ks * 32);
        *(float4*)&a1[4] = *(const float4*)(xr1 + ks * 32 + 4);
        bf16x8 a0h, a0l, a1h, a1l;
        #pragma unroll
        for (int j = 0; j < 8; j++) {
            short h0 = f2bf(a0[j]); a0h[j] = h0; a0l[j] = f2bf(a0[j] - bf2f(h0));
            short h1 = f2bf(a1[j]); a1h[j] = h1; a1l[j] = f2bf(a1[j] - bf2f(h1));
        }
        int kb = ks * 32 + quad * 8;
        int koff = kb ^ (ln << 3);
        #pragma unroll
        for (int ct = 0; ct < 8; ct++) {
            int pos = (ct * 16 + ln) * C + koff;
            bf16x8 bh = *(bf16x8*)&Bh[pos];
            bf16x8 bl = *(bf16x8*)&Bl[pos];
            acc[0][ct] = __builtin_amdgcn_mfma_f32_16x16x32_bf16(a0h, bh, acc[0][ct], 0, 0, 0);
            acc[0][ct] = __builtin_amdgcn_mfma_f32_16x16x32_bf16(a0l, bh, acc[0][ct], 0, 0, 0);
            acc[0][ct] = __builtin_amdgcn_mfma_f32_16x16x32_bf16(a0h, bl, acc[0][ct], 0, 0, 0);
            acc[1][ct] = __builtin_amdgcn_mfma_f32_16x16x32_bf16(a1h, bh, acc[1][ct], 0, 0, 0);
            acc[1][ct] = __builtin_amdgcn_mfma_f32_16x16x32_bf16(a1l, bh, acc[1][ct], 0, 0, 0);
            acc[1][ct] = __builtin_amdgcn_mfma_f32_16x16x32_bf16(a1h, bl, acc[1][ct], 0, 0, 0);
        }
    }

    // D layout (m89): col = lane&15, row = quad*4 + reg
    __half* H = (__half*)xwh;
    #pragma unroll
    for (int mt = 0; mt < 2; mt++) {
        int rbase = r0 + mt * 16 + quad * 4;
        #pragma unroll
        for (int ct = 0; ct < 8; ct++) {
            int col = ct * 16 + ln;
            #pragma unroll
            for (int reg = 0; reg < 4; reg++) {
                int r = rbase + reg;
                if (r < N) H[(size_t)r * C + col] = __float2half(acc[mt][ct][reg]);
            }
        }
    }
}

// ---------------------------------------------------------------- gather: wave per node, 4-wide unroll, nt ld/st
__global__ __launch_bounds__(256) void k_gather(const unsigned* __restrict__ xwh,
                                                const int* __restrict__ offs,
                                                const unsigned long long* __restrict__ epack,
                                                const float* __restrict__ dinv,
                                                const float* __restrict__ b_conv,
                                                float* __restrict__ out, int N) {
    int t = threadIdx.x;
    int v = blockIdx.x * 4 + (t >> 6);
    int lane = t & 63;
    if (v >= N) return;
    float dv = dinv[v];
    unsigned uv = xwh[(size_t)v * 64 + lane];
    __half2 hv = *(__half2*)&uv;
    float acc0 = dv * dv * __low2float(hv);
    float acc1 = dv * dv * __high2float(hv);
    int e0 = offs[v], e1 = offs[v + 1];
    int e = e0;
    for (; e + 3 < e1; e += 4) {
        unsigned long long p0 = __builtin_nontemporal_load(&epack[e + 0]);
        unsigned long long p1 = __builtin_nontemporal_load(&epack[e + 1]);
        unsigned long long p2 = __builtin_nontemporal_load(&epack[e + 2]);
        unsigned long long p3 = __builtin_nontemporal_load(&epack[e + 3]);
        unsigned u0 = xwh[(size_t)(unsigned)(p0 & 0xFFFFFFFFull) * 64 + lane];
        unsigned u1 = xwh[(size_t)(unsigned)(p1 & 0xFFFFFFFFull) * 64 + lane];
        unsigned u2 = xwh[(size_t)(unsigned)(p2 & 0xFFFFFFFFull) * 64 + lane];
        unsigned u3 = xwh[(size_t)(unsigned)(p3 & 0xFFFFFFFFull) * 64 + lane];
        float n0 = __uint_as_float((unsigned)(p0 >> 32));
        float n1 = __uint_as_float((unsigned)(p1 >> 32));
        float n2 = __uint_as_float((unsigned)(p2 >> 32));
        float n3 = __uint_as_float((unsigned)(p3 >> 32));
        __half2 h0 = *(__half2*)&u0, h1 = *(__half2*)&u1;
        __half2 h2 = *(__half2*)&u2, h3 = *(__half2*)&u3;
        acc0 += n0 * __low2float(h0) + n1 * __low2float(h1)
              + n2 * __low2float(h2) + n3 * __low2float(h3);
        acc1 += n0 * __high2float(h0) + n1 * __high2float(h1)
              + n2 * __high2float(h2) + n3 * __high2float(h3);
    }
    for (; e < e1; e++) {
        unsigned long long pA = __builtin_nontemporal_load(&epack[e]);
        unsigned uA = xwh[(size_t)(unsigned)(pA & 0xFFFFFFFFull) * 64 + lane];
        float nA = __uint_as_float((unsigned)(pA >> 32));
        __half2 hA = *(__half2*)&uA;
        acc0 += nA * __low2float(hA);
        acc1 += nA * __high2float(hA);
    }
    const float2* b2 = (const float2*)b_conv;
    float2 bb = b2[lane];
    unsigned long long ov = ((unsigned long long)__float_as_uint(acc1 + bb.y) << 32)
                          |  (unsigned long long)__float_as_uint(acc0 + bb.x);
    __builtin_nontemporal_store(ov, (unsigned long long*)(out + (size_t)v * C) + lane);
}

// ---------------------------------------------------------------- launcher
extern "C" void kernel_launch(void* const* d_in, const int* in_sizes, int n_in,
                              void* d_out, int out_size, void* d_ws, size_t ws_size,
                              hipStream_t stream) {
    const float* X      = (const float*)d_in[0];
    const float* ew     = (const float*)d_in[1];
    const float* p      = (const float*)d_in[2];
    const float* W_ih   = (const float*)d_in[3];
    const float* W_hh   = (const float*)d_in[4];
    const float* b_ih   = (const float*)d_in[5];
    const float* b_hh   = (const float*)d_in[6];
    const float* W_conv = (const float*)d_in[7];
    const float* b_conv = (const float*)d_in[8];
    const int*   ei     = (const int*)d_in[9];
    const int N = in_sizes[0] / C;
    const int E = in_sizes[1];
    float* out = (float*)d_out;
    const int NB = (N + 255) / 256;

    char* w = (char*)d_ws;
    auto alloc = [&](size_t bytes) -> void* {
        void* r = (void*)w;
        w += (bytes + 255) & ~(size_t)255;
        return r;
    };
    // zero-init region: pack + hist + nc (single memset)
    unsigned long long* pack = (unsigned long long*)alloc((size_t)N * 8);
    int*   hist   = (int*)alloc(HB * 4);
    int*   nc     = (int*)alloc(256);
    size_t zbytes = (size_t)(w - (char*)d_ws);
    float* scores = (float*)alloc((size_t)N * 4);
    float* dinv   = (float*)alloc((size_t)N * 4);
    int*   offs   = (int*)alloc((size_t)(N + 1) * 4);
    int*   cursor = (int*)alloc((size_t)N * 4);
    int*   pref   = (int*)alloc((size_t)N * 4);
    int*   bsum   = (int*)alloc((size_t)NB * 4);
    unsigned long long* cand = (unsigned long long*)alloc((size_t)NS * 8);
    int*   tidx   = (int*)alloc(C * 4);
    float* gate   = (float*)alloc(C * 4);
    float* wnewT  = (float*)alloc((size_t)C * C * 4);
    unsigned long long* epack = (unsigned long long*)alloc((size_t)E * 8);
    unsigned* xwh = (unsigned*)alloc((size_t)N * 64 * 4);

    hipMemsetAsync(d_ws, 0, zbytes, stream);
    int edgeBlocks = (E / 2 + 1023) / 1024;
    k_front<<<SHB + edgeBlocks, 1024, 0, stream>>>(X, p, scores, hist, ei, ew, pack, N, E);
    k_filter<<<NB, 256, 0, stream>>>(scores, hist, nc, cand, N);
    k_sel<<<1, 1024, 0, stream>>>(cand, nc, p, tidx, gate);
    k_gru<<<C / 2, 256, 0, stream>>>(X, tidx, gate, W_conv, W_ih, W_hh, b_ih, b_hh, wnewT);
    k_scan1<<<NB, 256, 0, stream>>>(pack, pref, bsum, dinv, N);
    k_scan3<<<NB, 256, 0, stream>>>(pref, bsum, offs, cursor, N, E, NB);
    k_scatter<<<(E + 255) / 256, 256, 0, stream>>>(ei, ew, dinv, cursor, epack, E);
    k_xw<<<(N + 127) / 128, 256, 0, stream>>>(X, wnewT, xwh, N);
    k_gather<<<(N + 3) / 4, 256, 0, stream>>>(xwh, offs, epack, dinv, b_conv, out, N);
}

// Round 9
// 285.427 us; speedup vs baseline: 1.1316x; 1.0428x over previous
//
#include <hip/hip_runtime.h>
#include <hip/hip_fp16.h>
#include <math.h>

#define C 128
#define HB 2048          // histogram buckets (top 11 bits of ordered float)
#define NS 4096          // candidate capacity (pow2 for bitonic)
#define SHB 128          // score/hist blocks inside k_front
#define NCPY 8           // privatized copies (XCD count); copy(e) = (e>>8)&7 EVERYWHERE

typedef __attribute__((ext_vector_type(8))) short bf16x8;
typedef __attribute__((ext_vector_type(4))) float f32x4;

__device__ inline unsigned ord_f32(float f) {
    unsigned u = __float_as_uint(f);
    return u ^ ((u & 0x80000000u) ? 0xFFFFFFFFu : 0x80000000u);
}
__device__ inline float unord_f32(unsigned u) {
    return __uint_as_float(u ^ ((u & 0x80000000u) ? 0x80000000u : 0xFFFFFFFFu));
}
__device__ inline unsigned long long enc_w(float w) {
    return (1ULL << 40) | (unsigned long long)(w * 67108864.0f + 0.5f);  // cnt<<40 | fixed26(w)
}
__device__ inline short f2bf(float f) {        // RNE float -> bf16 bits
    unsigned u = __float_as_uint(f);
    return (short)((u + 0x7FFFu + ((u >> 16) & 1u)) >> 16);
}
__device__ inline float bf2f(short s) {
    return __uint_as_float(((unsigned)(unsigned short)s) << 16);
}

// ---------------------------------------------------------------- front: blocks [0,SHB) scores+hist, rest deg/cnt
__global__ __launch_bounds__(1024) void k_front(const float* __restrict__ X,
                                                const float* __restrict__ p,
                                                float* __restrict__ scores,
                                                int* __restrict__ hist,
                                                const int* __restrict__ ei,
                                                const float* __restrict__ ew,
                                                unsigned long long* __restrict__ pack8,
                                                int N, int E) {
    int t = threadIdx.x;
    if (blockIdx.x < SHB) {
        __shared__ int lh[HB];
        for (int i = t; i < HB; i += 1024) lh[i] = 0;
        __syncthreads();
        int gw   = blockIdx.x * 16 + (t >> 6);     // SHB*16 = 2048 waves
        int lane = t & 63;
        for (int r = gw; r < N; r += 2048) {
            const float* xr = X + (size_t)r * C;
            float a = xr[lane] * p[lane] + xr[lane + 64] * p[lane + 64];
            #pragma unroll
            for (int o = 32; o; o >>= 1) a += __shfl_down(a, o);
            if (lane == 0) {
                scores[r] = a;
                atomicAdd(&lh[ord_f32(a) >> 21], 1);
            }
        }
        __syncthreads();
        for (int i = t; i < HB; i += 1024) {
            int v = lh[i];
            if (v) atomicAdd(&hist[i], v);
        }
    } else {
        // edges: base multiple of 2048 per block; e>>8 & 7 == (t>>7)&7 for both e and e+1
        unsigned long long* pk = pack8 + (size_t)((t >> 7) & (NCPY - 1)) * N;
        int e = ((blockIdx.x - SHB) * 1024 + t) * 2;
        if (e + 1 < E) {
            int2 d2   = *(const int2*)(ei + E + e);
            float2 w2 = *(const float2*)(ew + e);
            atomicAdd(&pk[d2.x], enc_w(w2.x));
            atomicAdd(&pk[d2.y], enc_w(w2.y));
        } else if (e < E) {
            atomicAdd(&pk[ei[E + e]], enc_w(ew[e]));
        }
    }
}

// ---------------------------------------------------------------- filter with inline threshold scan
__global__ __launch_bounds__(256) void k_filter(const float* __restrict__ scores,
                                                const int* __restrict__ hist,
                                                int* __restrict__ nc,
                                                unsigned long long* __restrict__ cand, int N) {
    __shared__ int sc[256];
    __shared__ int sT;
    int t = threadIdx.x;
    int loc[8];
    int sum = 0;
    #pragma unroll
    for (int s = 0; s < 8; s++) {
        loc[s] = hist[HB - 1 - (t * 8 + s)];
        sum += loc[s];
    }
    sc[t] = sum;
    __syncthreads();
    for (int off = 1; off < 256; off <<= 1) {
        int v = (t >= off) ? sc[t - off] : 0;
        __syncthreads();
        sc[t] += v;
        __syncthreads();
    }
    int run = sc[t] - sum;
    #pragma unroll
    for (int s = 0; s < 8; s++) {
        int b = HB - 1 - (t * 8 + s);
        int nr = run + loc[s];
        if (run < C && nr >= C) sT = b;
        run = nr;
    }
    __syncthreads();
    int T = sT;
    int i = blockIdx.x * 256 + t;
    if (i < N) {
        unsigned u = ord_f32(scores[i]);
        if ((int)(u >> 21) >= T) {
            int pos = atomicAdd(nc, 1);
            if (pos < NS)
                cand[pos] = ((unsigned long long)u << 32) | (unsigned)(~(unsigned)i);
        }
    }
}

// ---------------------------------------------------------------- adaptive bitonic sort desc, emit top-128
__global__ __launch_bounds__(1024) void k_sel(const unsigned long long* __restrict__ cand,
                                              const int* __restrict__ nc,
                                              const float* __restrict__ p,
                                              int* __restrict__ tidx, float* __restrict__ gate) {
    __shared__ unsigned long long sk[NS];
    __shared__ float red[16];
    __shared__ float s_pn;
    int t = threadIdx.x;
    int M = *nc; if (M > NS) M = NS;
    int S = 256; while (S < M) S <<= 1;          // sort size: pow2 >= max(M,256)
    for (int i = t; i < S; i += 1024) sk[i] = (i < M) ? cand[i] : 0ULL;
    float pv = 0.f;
    if (t < C) { float x = p[t]; pv = x * x; }
    #pragma unroll
    for (int o = 32; o; o >>= 1) pv += __shfl_down(pv, o);
    if ((t & 63) == 0) red[t >> 6] = pv;
    __syncthreads();
    if (t == 0) {
        float s = 0.f;
        for (int i = 0; i < 16; i++) s += red[i];
        s_pn = sqrtf(s);
    }
    for (int k = 2; k <= S; k <<= 1) {
        for (int j = k >> 1; j > 0; j >>= 1) {
            __syncthreads();
            for (int idx = t; idx < S; idx += 1024) {
                int l = idx ^ j;
                if (l > idx) {
                    unsigned long long a = sk[idx], b = sk[l];
                    bool desc = (idx & k) == 0;
                    if (desc ? (a < b) : (a > b)) { sk[idx] = b; sk[l] = a; }
                }
            }
        }
    }
    __syncthreads();
    if (t < C) {
        unsigned long long g = sk[t];
        tidx[t] = (int)(~(unsigned)(g & 0xFFFFFFFFull));
        gate[t] = tanhf(unord_f32((unsigned)(g >> 32)) / s_pn);
    }
}

// ---------------------------------------------------------------- scan A: per-block scan of summed counts + dinv
__global__ __launch_bounds__(256) void k_scan1(const unsigned long long* __restrict__ pack8,
                                               int* __restrict__ pref, int* __restrict__ bsum,
                                               float* __restrict__ dinv, int N) {
    __shared__ int sc[256];
    int t = threadIdx.x;
    int i = blockIdx.x * 256 + t;
    int v = 0;
    if (i < N) {
        unsigned long long s = 0;
        #pragma unroll
        for (int c = 0; c < NCPY; c++) s += pack8[(size_t)c * N + i];
        v = (int)(s >> 40);
        float deg = 1.0f + (float)(s & 0xFFFFFFFFFFULL) * (1.0f / 67108864.0f);
        dinv[i] = rsqrtf(deg);
    }
    sc[t] = v;
    __syncthreads();
    for (int off = 1; off < 256; off <<= 1) {
        int u = (t >= off) ? sc[t - off] : 0;
        __syncthreads();
        sc[t] += u;
        __syncthreads();
    }
    if (i < N) pref[i] = sc[t] - v;
    if (t == 255) bsum[blockIdx.x] = sc[255];
}

// ---------------------------------------------------------------- scan B+C merged: offs + per-copy cursors
__global__ __launch_bounds__(256) void k_scan3(const int* __restrict__ pref, const int* __restrict__ bsum,
                                               const unsigned long long* __restrict__ pack8,
                                               int* __restrict__ offs, int* __restrict__ cursor8,
                                               int N, int E, int NB) {
    __shared__ int red[4];
    int t = threadIdx.x, bid = blockIdx.x;
    int v = (t < NB && t < bid) ? bsum[t] : 0;
    #pragma unroll
    for (int o = 32; o; o >>= 1) v += __shfl_down(v, o);
    if ((t & 63) == 0) red[t >> 6] = v;
    __syncthreads();
    int base = red[0] + red[1] + red[2] + red[3];
    int i = bid * 256 + t;
    if (i < N) {
        int run = base + pref[i];
        offs[i] = run;
        #pragma unroll
        for (int c = 0; c < NCPY; c++) {
            cursor8[(size_t)c * N + i] = run;
            run += (int)(pack8[(size_t)c * N + i] >> 40);
        }
    }
    if (i == 0) offs[N] = E;
}

// ---------------------------------------------------------------- GRU step (X_tilde folded in) -> W_new^T
__global__ __launch_bounds__(256) void k_gru(const float* __restrict__ X,
                                             const int* __restrict__ tidx,
                                             const float* __restrict__ gate,
                                             const float* __restrict__ Wc,
                                             const float* __restrict__ W_ih, const float* __restrict__ W_hh,
                                             const float* __restrict__ b_ih, const float* __restrict__ b_hh,
                                             float* __restrict__ wnewT) {
    int t = threadIdx.x;
    int i = t & 127;
    int j = blockIdx.x * 2 + (t >> 7);
    int src = tidx[i];
    float g = gate[i];
    const float4* xr   = (const float4*)(X + (size_t)src * C);
    const float4* hr   = (const float4*)(Wc + (size_t)i * C);
    const float4* wri  = (const float4*)(W_ih + (size_t)j * C);
    const float4* wzi  = (const float4*)(W_ih + (size_t)(C + j) * C);
    const float4* wni  = (const float4*)(W_ih + (size_t)(2 * C + j) * C);
    const float4* wrh  = (const float4*)(W_hh + (size_t)j * C);
    const float4* wzh  = (const float4*)(W_hh + (size_t)(C + j) * C);
    const float4* wnh  = (const float4*)(W_hh + (size_t)(2 * C + j) * C);
    float gir = 0, giz = 0, gin = 0, ghr = 0, ghz = 0, ghn = 0;
    #pragma unroll 8
    for (int k4 = 0; k4 < C / 4; k4++) {
        float4 x = xr[k4], h = hr[k4], a;
        a = wri[k4]; gir += x.x * a.x + x.y * a.y + x.z * a.z + x.w * a.w;
        a = wzi[k4]; giz += x.x * a.x + x.y * a.y + x.z * a.z + x.w * a.w;
        a = wni[k4]; gin += x.x * a.x + x.y * a.y + x.z * a.z + x.w * a.w;
        a = wrh[k4]; ghr += h.x * a.x + h.y * a.y + h.z * a.z + h.w * a.w;
        a = wzh[k4]; ghz += h.x * a.x + h.y * a.y + h.z * a.z + h.w * a.w;
        a = wnh[k4]; ghn += h.x * a.x + h.y * a.y + h.z * a.z + h.w * a.w;
    }
    gir = g * gir + b_ih[j];         ghr += b_hh[j];
    giz = g * giz + b_ih[C + j];     ghz += b_hh[C + j];
    gin = g * gin + b_ih[2 * C + j]; ghn += b_hh[2 * C + j];
    float r = 1.f / (1.f + expf(-(gir + ghr)));
    float z = 1.f / (1.f + expf(-(giz + ghz)));
    float n = tanhf(gin + r * ghn);
    float wn = (1.f - z) * n + z * Wc[(size_t)i * C + j];
    wnewT[(size_t)j * C + i] = wn;
}

// ---------------------------------------------------------------- edge scatter into CSR order (per-copy cursor)
// copy(e) = (e>>8)&7 == blockIdx&7 here (256 edges/block) — XCD-aligned and
// IDENTICAL to k_front's reservation mapping (correctness requirement).
__global__ __launch_bounds__(256) void k_scatter(const int* __restrict__ ei, const float* __restrict__ ew,
                                                 const float* __restrict__ dinv, int* __restrict__ cursor8,
                                                 unsigned* __restrict__ epack, int E, int N) {
    int e = blockIdx.x * 256 + threadIdx.x;
    if (e < E) {
        int* cur = cursor8 + (size_t)(blockIdx.x & (NCPY - 1)) * N;
        int s = ei[e], d = ei[E + e];
        float nm = dinv[s] * ew[e] * dinv[d];
        int pos = atomicAdd(&cur[d], 1);
        __half hn = __float2half(nm);
        unsigned pk = ((unsigned)*(unsigned short*)&hn << 16) | (unsigned)s;  // N < 65536
        __builtin_nontemporal_store(pk, &epack[pos]);
    }
}

// ---------------------------------------------------------------- Xw = X @ W_new^T via MFMA (split-bf16, ~fp32 acc)
__global__ __launch_bounds__(256) void k_xw(const float* __restrict__ X,
                                            const float* __restrict__ wnewT,
                                            unsigned* __restrict__ xwh, int N) {
    __shared__ short Bh[C * C];
    __shared__ short Bl[C * C];
    int t = threadIdx.x;
    for (int idx = t; idx < C * C; idx += 256) {
        int k = idx >> 7, c = idx & 127;       // wnewT[k*C+c] = W_new[c][k]
        float wv = wnewT[idx];
        short hi = f2bf(wv);
        float lo = wv - bf2f(hi);
        int pos = c * C + (k ^ ((c & 15) << 3));
        Bh[pos] = hi;
        Bl[pos] = f2bf(lo);
    }
    __syncthreads();

    int wave = t >> 6, lane = t & 63;
    int ln = lane & 15, quad = lane >> 4;
    int r0 = blockIdx.x * 128 + wave * 32;

    f32x4 acc[2][8];
    #pragma unroll
    for (int mt = 0; mt < 2; mt++)
        #pragma unroll
        for (int ct = 0; ct < 8; ct++) { acc[mt][ct][0] = 0.f; acc[mt][ct][1] = 0.f; acc[mt][ct][2] = 0.f; acc[mt][ct][3] = 0.f; }

    int row0 = r0 + ln;       if (row0 >= N) row0 = N - 1;
    int row1 = r0 + 16 + ln;  if (row1 >= N) row1 = N - 1;
    const float* xr0 = X + (size_t)row0 * C + quad * 8;
    const float* xr1 = X + (size_t)row1 * C + quad * 8;

    for (int ks = 0; ks < 4; ks++) {
        float a0[8], a1[8];
        *(float4*)&a0[0] = *(const float4*)(xr0 + ks * 32);
        *(float4*)&a0[4] = *(const float4*)(xr0 + ks * 32 + 4);
        *(float4*)&a1[0] = *(const float4*)(xr1 + ks * 32);
        *(float4*)&a1[4] = *(const float4*)(xr1 + ks * 32 + 4);
        bf16x8 a0h, a0l, a1h, a1l;
        #pragma unroll
        for (int j = 0; j < 8; j++) {
            short h0 = f2bf(a0[j]); a0h[j] = h0; a0l[j] = f2bf(a0[j] - bf2f(h0));
            short h1 = f2bf(a1[j]); a1h[j] = h1; a1l[j] = f2bf(a1[j] - bf2f(h1));
        }
        int kb = ks * 32 + quad * 8;
        int koff = kb ^ (ln << 3);
        #pragma unroll
        for (int ct = 0; ct < 8; ct++) {
            int pos = (ct * 16 + ln) * C + koff;
            bf16x8 bh = *(bf16x8*)&Bh[pos];
            bf16x8 bl = *(bf16x8*)&Bl[pos];
            acc[0][ct] = __builtin_amdgcn_mfma_f32_16x16x32_bf16(a0h, bh, acc[0][ct], 0, 0, 0);
            acc[0][ct] = __builtin_amdgcn_mfma_f32_16x16x32_bf16(a0l, bh, acc[0][ct], 0, 0, 0);
            acc[0][ct] = __builtin_amdgcn_mfma_f32_16x16x32_bf16(a0h, bl, acc[0][ct], 0, 0, 0);
            acc[1][ct] = __builtin_amdgcn_mfma_f32_16x16x32_bf16(a1h, bh, acc[1][ct], 0, 0, 0);
            acc[1][ct] = __builtin_amdgcn_mfma_f32_16x16x32_bf16(a1l, bh, acc[1][ct], 0, 0, 0);
            acc[1][ct] = __builtin_amdgcn_mfma_f32_16x16x32_bf16(a1h, bl, acc[1][ct], 0, 0, 0);
        }
    }

    // D layout (m89): col = lane&15, row = quad*4 + reg
    __half* H = (__half*)xwh;
    #pragma unroll
    for (int mt = 0; mt < 2; mt++) {
        int rbase = r0 + mt * 16 + quad * 4;
        #pragma unroll
        for (int ct = 0; ct < 8; ct++) {
            int col = ct * 16 + ln;
            #pragma unroll
            for (int reg = 0; reg < 4; reg++) {
                int r = rbase + reg;
                if (r < N) H[(size_t)r * C + col] = __float2half(acc[mt][ct][reg]);
            }
        }
    }
}

// ---------------------------------------------------------------- gather: wave per node, 8-wide unroll, nt ld/st
__global__ __launch_bounds__(256) void k_gather(const unsigned* __restrict__ xwh,
                                                const int* __restrict__ offs,
                                                const unsigned* __restrict__ epack,
                                                const float* __restrict__ dinv,
                                                const float* __restrict__ b_conv,
                                                float* __restrict__ out, int N) {
    int t = threadIdx.x;
    int v = blockIdx.x * 4 + (t >> 6);
    int lane = t & 63;
    if (v >= N) return;
    float dv = dinv[v];
    unsigned uv = xwh[(size_t)v * 64 + lane];
    __half2 hv = *(__half2*)&uv;
    float acc0 = dv * dv * __low2float(hv);
    float acc1 = dv * dv * __high2float(hv);
    int e0 = offs[v], e1 = offs[v + 1];
    int e = e0;
    for (; e + 7 < e1; e += 8) {
        unsigned pk[8];
        unsigned ux[8];
        #pragma unroll
        for (int j = 0; j < 8; j++) pk[j] = __builtin_nontemporal_load(&epack[e + j]);
        #pragma unroll
        for (int j = 0; j < 8; j++) ux[j] = xwh[(size_t)(pk[j] & 0xFFFFu) * 64 + lane];
        #pragma unroll
        for (int j = 0; j < 8; j++) {
            unsigned short hs = (unsigned short)(pk[j] >> 16);
            float nm = __half2float(*(__half*)&hs);
            __half2 h = *(__half2*)&ux[j];
            acc0 += nm * __low2float(h);
            acc1 += nm * __high2float(h);
        }
    }
    for (; e + 3 < e1; e += 4) {
        unsigned pk[4];
        unsigned ux[4];
        #pragma unroll
        for (int j = 0; j < 4; j++) pk[j] = __builtin_nontemporal_load(&epack[e + j]);
        #pragma unroll
        for (int j = 0; j < 4; j++) ux[j] = xwh[(size_t)(pk[j] & 0xFFFFu) * 64 + lane];
        #pragma unroll
        for (int j = 0; j < 4; j++) {
            unsigned short hs = (unsigned short)(pk[j] >> 16);
            float nm = __half2float(*(__half*)&hs);
            __half2 h = *(__half2*)&ux[j];
            acc0 += nm * __low2float(h);
            acc1 += nm * __high2float(h);
        }
    }
    for (; e < e1; e++) {
        unsigned pA = __builtin_nontemporal_load(&epack[e]);
        unsigned uA = xwh[(size_t)(pA & 0xFFFFu) * 64 + lane];
        unsigned short hs = (unsigned short)(pA >> 16);
        float nA = __half2float(*(__half*)&hs);
        __half2 hA = *(__half2*)&uA;
        acc0 += nA * __low2float(hA);
        acc1 += nA * __high2float(hA);
    }
    const float2* b2 = (const float2*)b_conv;
    float2 bb = b2[lane];
    unsigned long long ov = ((unsigned long long)__float_as_uint(acc1 + bb.y) << 32)
                          |  (unsigned long long)__float_as_uint(acc0 + bb.x);
    __builtin_nontemporal_store(ov, (unsigned long long*)(out + (size_t)v * C) + lane);
}

// ---------------------------------------------------------------- launcher
extern "C" void kernel_launch(void* const* d_in, const int* in_sizes, int n_in,
                              void* d_out, int out_size, void* d_ws, size_t ws_size,
                              hipStream_t stream) {
    const float* X      = (const float*)d_in[0];
    const float* ew     = (const float*)d_in[1];
    const float* p      = (const float*)d_in[2];
    const float* W_ih   = (const float*)d_in[3];
    const float* W_hh   = (const float*)d_in[4];
    const float* b_ih   = (const float*)d_in[5];
    const float* b_hh   = (const float*)d_in[6];
    const float* W_conv = (const float*)d_in[7];
    const float* b_conv = (const float*)d_in[8];
    const int*   ei     = (const int*)d_in[9];
    const int N = in_sizes[0] / C;
    const int E = in_sizes[1];
    float* out = (float*)d_out;
    const int NB = (N + 255) / 256;

    char* w = (char*)d_ws;
    auto alloc = [&](size_t bytes) -> void* {
        void* r = (void*)w;
        w += (bytes + 255) & ~(size_t)255;
        return r;
    };
    // zero-init region: pack8 + hist + nc (single memset)
    unsigned long long* pack8 = (unsigned long long*)alloc((size_t)NCPY * N * 8);
    int*   hist   = (int*)alloc(HB * 4);
    int*   nc     = (int*)alloc(256);
    size_t zbytes = (size_t)(w - (char*)d_ws);
    float* scores = (float*)alloc((size_t)N * 4);
    float* dinv   = (float*)alloc((size_t)N * 4);
    int*   offs   = (int*)alloc((size_t)(N + 1) * 4);
    int*   cursor8= (int*)alloc((size_t)NCPY * N * 4);
    int*   pref   = (int*)alloc((size_t)N * 4);
    int*   bsum   = (int*)alloc((size_t)NB * 4);
    unsigned long long* cand = (unsigned long long*)alloc((size_t)NS * 8);
    int*   tidx   = (int*)alloc(C * 4);
    float* gate   = (float*)alloc(C * 4);
    float* wnewT  = (float*)alloc((size_t)C * C * 4);
    unsigned* epack = (unsigned*)alloc((size_t)E * 4);
    unsigned* xwh = (unsigned*)alloc((size_t)N * 64 * 4);

    hipMemsetAsync(d_ws, 0, zbytes, stream);
    int edgeBlocks = (E / 2 + 1023) / 1024;
    k_front<<<SHB + edgeBlocks, 1024, 0, stream>>>(X, p, scores, hist, ei, ew, pack8, N, E);
    k_filter<<<NB, 256, 0, stream>>>(scores, hist, nc, cand, N);
    k_sel<<<1, 1024, 0, stream>>>(cand, nc, p, tidx, gate);
    k_gru<<<C / 2, 256, 0, stream>>>(X, tidx, gate, W_conv, W_ih, W_hh, b_ih, b_hh, wnewT);
    k_scan1<<<NB, 256, 0, stream>>>(pack8, pref, bsum, dinv, N);
    k_scan3<<<NB, 256, 0, stream>>>(pref, bsum, pack8, offs, cursor8, N, E, NB);
    k_scatter<<<(E + 255) / 256, 256, 0, stream>>>(ei, ew, dinv, cursor8, epack, E, N);
    k_xw<<<(N + 127) / 128, 256, 0, stream>>>(X, wnewT, xwh, N);
    k_gather<<<(N + 3) / 4, 256, 0, stream>>>(xwh, offs, epack, dinv, b_conv, out, N);
}

// Round 10
// 232.687 us; speedup vs baseline: 1.3881x; 1.2267x over previous
//
#include <hip/hip_runtime.h>
#include <hip/hip_fp16.h>
#include <math.h>

#define C 128
#define HB 2048          // score histogram buckets (top 11 bits of ordered float)
#define NS 4096          // candidate capacity (pow2 for bitonic)
#define SHB 128          // score/hist blocks inside k_front

typedef __attribute__((ext_vector_type(8))) short bf16x8;
typedef __attribute__((ext_vector_type(4))) float f32x4;

__device__ inline unsigned ord_f32(float f) {
    unsigned u = __float_as_uint(f);
    return u ^ ((u & 0x80000000u) ? 0xFFFFFFFFu : 0x80000000u);
}
__device__ inline float unord_f32(unsigned u) {
    return __uint_as_float(u ^ ((u & 0x80000000u) ? 0x80000000u : 0xFFFFFFFFu));
}
__device__ inline short f2bf(float f) {        // RNE float -> bf16 bits
    unsigned u = __float_as_uint(f);
    return (short)((u + 0x7FFFu + ((u >> 16) & 1u)) >> 16);
}
__device__ inline float bf2f(short s) {
    return __uint_as_float(((unsigned)(unsigned short)s) << 16);
}

// ---------------------------------------------------------------- front: blocks [0,SHB) scores+hist; rest: MSD edge hist
// edge blocks: 2048 edges each, LDS histogram over dst>>8 (NBIN bins), plain stores (no global atomics)
__global__ __launch_bounds__(1024) void k_front(const float* __restrict__ X,
                                                const float* __restrict__ p,
                                                float* __restrict__ scores,
                                                int* __restrict__ hist,
                                                const int* __restrict__ ei,
                                                int* __restrict__ rh,
                                                int N, int E, int NBIN, int NBLKE) {
    int t = threadIdx.x;
    if (blockIdx.x < SHB) {
        __shared__ int lh[HB];
        for (int i = t; i < HB; i += 1024) lh[i] = 0;
        __syncthreads();
        int gw   = blockIdx.x * 16 + (t >> 6);
        int lane = t & 63;
        for (int r = gw; r < N; r += 2048) {
            const float* xr = X + (size_t)r * C;
            float a = xr[lane] * p[lane] + xr[lane + 64] * p[lane + 64];
            #pragma unroll
            for (int o = 32; o; o >>= 1) a += __shfl_down(a, o);
            if (lane == 0) {
                scores[r] = a;
                atomicAdd(&lh[ord_f32(a) >> 21], 1);
            }
        }
        __syncthreads();
        for (int i = t; i < HB; i += 1024) {
            int v = lh[i];
            if (v) atomicAdd(&hist[i], v);
        }
    } else {
        __shared__ int bh[256];
        for (int i = t; i < 256; i += 1024) bh[i] = 0;
        __syncthreads();
        int eb = blockIdx.x - SHB;
        int e = eb * 2048 + t * 2;
        if (e + 1 < E) {
            int2 d2 = *(const int2*)(ei + E + e);
            atomicAdd(&bh[d2.x >> 8], 1);
            atomicAdd(&bh[d2.y >> 8], 1);
        } else if (e < E) {
            atomicAdd(&bh[ei[E + e] >> 8], 1);
        }
        __syncthreads();
        for (int i = t; i < NBIN; i += 1024) rh[(size_t)i * NBLKE + eb] = bh[i];
    }
}

// ---------------------------------------------------------------- radix scan A: per-bin exclusive scan over blocks
__global__ __launch_bounds__(512) void k_rscanA(int* __restrict__ rh, int* __restrict__ tot, int NBLKE) {
    __shared__ int sc[512];
    int t = threadIdx.x;
    int bin = blockIdx.x;
    int v = (t < NBLKE) ? rh[(size_t)bin * NBLKE + t] : 0;
    sc[t] = v;
    __syncthreads();
    for (int off = 1; off < 512; off <<= 1) {
        int u = (t >= off) ? sc[t - off] : 0;
        __syncthreads();
        sc[t] += u;
        __syncthreads();
    }
    if (t < NBLKE) rh[(size_t)bin * NBLKE + t] = sc[t] - v;
    if (t == 511) tot[bin] = sc[511];
}

// ---------------------------------------------------------------- radix scan B: bin bases
__global__ __launch_bounds__(256) void k_rscanB(const int* __restrict__ tot, int* __restrict__ binbase,
                                                int NBIN, int E) {
    __shared__ int sc[256];
    int t = threadIdx.x;
    int v = (t < NBIN) ? tot[t] : 0;
    sc[t] = v;
    __syncthreads();
    for (int off = 1; off < 256; off <<= 1) {
        int u = (t >= off) ? sc[t - off] : 0;
        __syncthreads();
        sc[t] += u;
        __syncthreads();
    }
    if (t < NBIN) binbase[t] = sc[t] - v;
    if (t == 0) binbase[NBIN] = E;
}

// ---------------------------------------------------------------- radix scatter: edges -> dst buckets (LDS cursors only)
__global__ __launch_bounds__(1024) void k_rscat(const int* __restrict__ ei, const float* __restrict__ ew,
                                                const int* __restrict__ rh, const int* __restrict__ binbase,
                                                unsigned long long* __restrict__ sorted,
                                                int E, int NBIN, int NBLKE) {
    __shared__ int cur[256];
    int t = threadIdx.x;
    int eb = blockIdx.x;
    for (int i = t; i < NBIN; i += 1024) cur[i] = binbase[i] + rh[(size_t)i * NBLKE + eb];
    __syncthreads();
    int e = eb * 2048 + t * 2;
    #pragma unroll
    for (int j = 0; j < 2; j++) {
        int ee = e + j;
        if (ee < E) {
            int s = ei[ee], d = ei[E + ee];
            float w = ew[ee];
            int pos = atomicAdd(&cur[d >> 8], 1);
            unsigned long long pk = ((unsigned long long)(unsigned)d << 48)
                                  | ((unsigned long long)(unsigned short)s << 32)
                                  |  (unsigned long long)__float_as_uint(w);
            sorted[pos] = pk;
        }
    }
}

// ---------------------------------------------------------------- per-bucket: counting sort by dst&255 + offs/deg/dinv
__global__ __launch_bounds__(1024) void k_bin(const unsigned long long* __restrict__ sorted,
                                              const int* __restrict__ binbase,
                                              int* __restrict__ offs, float* __restrict__ dinv,
                                              unsigned* __restrict__ epack,
                                              int N, int E, int NBIN) {
    __shared__ int cnt[256];
    __shared__ float wsum[256];
    __shared__ int sc[256];
    __shared__ int cur2[256];
    int t = threadIdx.x;
    int b = blockIdx.x;
    int s0 = binbase[b], s1 = binbase[b + 1];
    for (int i = t; i < 256; i += 1024) { cnt[i] = 0; wsum[i] = 0.f; }
    __syncthreads();
    for (int i = s0 + t; i < s1; i += 1024) {
        unsigned long long pk = sorted[i];
        int d8 = (int)(pk >> 48) & 255;
        float w = __uint_as_float((unsigned)(pk & 0xFFFFFFFFull));
        atomicAdd(&cnt[d8], 1);
        atomicAdd(&wsum[d8], w);
    }
    __syncthreads();
    // exclusive scan of cnt (first 256 threads; all threads hit syncs)
    int v = (t < 256) ? cnt[t] : 0;
    if (t < 256) sc[t] = v;
    __syncthreads();
    for (int off = 1; off < 256; off <<= 1) {
        int u = (t < 256 && t >= off) ? sc[t - off] : 0;
        __syncthreads();
        if (t < 256) sc[t] += u;
        __syncthreads();
    }
    if (t < 256) {
        int loff = sc[t] - v;
        cur2[t] = s0 + loff;
        int node = b * 256 + t;
        if (node < N) {
            offs[node] = s0 + loff;
            dinv[node] = rsqrtf(1.0f + wsum[t]);
        }
    }
    if (b == NBIN - 1 && t == 0) offs[N] = E;
    __syncthreads();
    for (int i = s0 + t; i < s1; i += 1024) {
        unsigned long long pk = sorted[i];
        int d8 = (int)(pk >> 48) & 255;
        unsigned src = (unsigned)((pk >> 32) & 0xFFFFu);
        float w = __uint_as_float((unsigned)(pk & 0xFFFFFFFFull));
        int pos = atomicAdd(&cur2[d8], 1);
        __half hw = __float2half(w);
        epack[pos] = ((unsigned)*(unsigned short*)&hw << 16) | src;
    }
}

// ---------------------------------------------------------------- norm: fold dinv[src] into edge value
__global__ __launch_bounds__(256) void k_norm(unsigned* __restrict__ epack,
                                              const float* __restrict__ dinv, int E) {
    int e = blockIdx.x * 256 + threadIdx.x;
    if (e < E) {
        unsigned u = epack[e];
        unsigned src = u & 0xFFFFu;
        unsigned short hs = (unsigned short)(u >> 16);
        float m = __half2float(*(__half*)&hs) * dinv[src];
        __half hm = __float2half(m);
        epack[e] = ((unsigned)*(unsigned short*)&hm << 16) | src;
    }
}

// ---------------------------------------------------------------- filter with inline threshold scan
__global__ __launch_bounds__(256) void k_filter(const float* __restrict__ scores,
                                                const int* __restrict__ hist,
                                                int* __restrict__ nc,
                                                unsigned long long* __restrict__ cand, int N) {
    __shared__ int sc[256];
    __shared__ int sT;
    int t = threadIdx.x;
    int loc[8];
    int sum = 0;
    #pragma unroll
    for (int s = 0; s < 8; s++) {
        loc[s] = hist[HB - 1 - (t * 8 + s)];
        sum += loc[s];
    }
    sc[t] = sum;
    __syncthreads();
    for (int off = 1; off < 256; off <<= 1) {
        int v = (t >= off) ? sc[t - off] : 0;
        __syncthreads();
        sc[t] += v;
        __syncthreads();
    }
    int run = sc[t] - sum;
    #pragma unroll
    for (int s = 0; s < 8; s++) {
        int b = HB - 1 - (t * 8 + s);
        int nr = run + loc[s];
        if (run < C && nr >= C) sT = b;
        run = nr;
    }
    __syncthreads();
    int T = sT;
    int i = blockIdx.x * 256 + t;
    if (i < N) {
        unsigned u = ord_f32(scores[i]);
        if ((int)(u >> 21) >= T) {
            int pos = atomicAdd(nc, 1);
            if (pos < NS)
                cand[pos] = ((unsigned long long)u << 32) | (unsigned)(~(unsigned)i);
        }
    }
}

// ---------------------------------------------------------------- adaptive bitonic sort desc, emit top-128
__global__ __launch_bounds__(1024) void k_sel(const unsigned long long* __restrict__ cand,
                                              const int* __restrict__ nc,
                                              const float* __restrict__ p,
                                              int* __restrict__ tidx, float* __restrict__ gate) {
    __shared__ unsigned long long sk[NS];
    __shared__ float red[16];
    __shared__ float s_pn;
    int t = threadIdx.x;
    int M = *nc; if (M > NS) M = NS;
    int S = 256; while (S < M) S <<= 1;
    for (int i = t; i < S; i += 1024) sk[i] = (i < M) ? cand[i] : 0ULL;
    float pv = 0.f;
    if (t < C) { float x = p[t]; pv = x * x; }
    #pragma unroll
    for (int o = 32; o; o >>= 1) pv += __shfl_down(pv, o);
    if ((t & 63) == 0) red[t >> 6] = pv;
    __syncthreads();
    if (t == 0) {
        float s = 0.f;
        for (int i = 0; i < 16; i++) s += red[i];
        s_pn = sqrtf(s);
    }
    for (int k = 2; k <= S; k <<= 1) {
        for (int j = k >> 1; j > 0; j >>= 1) {
            __syncthreads();
            for (int idx = t; idx < S; idx += 1024) {
                int l = idx ^ j;
                if (l > idx) {
                    unsigned long long a = sk[idx], b = sk[l];
                    bool desc = (idx & k) == 0;
                    if (desc ? (a < b) : (a > b)) { sk[idx] = b; sk[l] = a; }
                }
            }
        }
    }
    __syncthreads();
    if (t < C) {
        unsigned long long g = sk[t];
        tidx[t] = (int)(~(unsigned)(g & 0xFFFFFFFFull));
        gate[t] = tanhf(unord_f32((unsigned)(g >> 32)) / s_pn);
    }
}

// ---------------------------------------------------------------- GRU step (X_tilde folded in) -> W_new^T
__global__ __launch_bounds__(256) void k_gru(const float* __restrict__ X,
                                             const int* __restrict__ tidx,
                                             const float* __restrict__ gate,
                                             const float* __restrict__ Wc,
                                             const float* __restrict__ W_ih, const float* __restrict__ W_hh,
                                             const float* __restrict__ b_ih, const float* __restrict__ b_hh,
                                             float* __restrict__ wnewT) {
    int t = threadIdx.x;
    int i = t & 127;
    int j = blockIdx.x * 2 + (t >> 7);
    int src = tidx[i];
    float g = gate[i];
    const float4* xr   = (const float4*)(X + (size_t)src * C);
    const float4* hr   = (const float4*)(Wc + (size_t)i * C);
    const float4* wri  = (const float4*)(W_ih + (size_t)j * C);
    const float4* wzi  = (const float4*)(W_ih + (size_t)(C + j) * C);
    const float4* wni  = (const float4*)(W_ih + (size_t)(2 * C + j) * C);
    const float4* wrh  = (const float4*)(W_hh + (size_t)j * C);
    const float4* wzh  = (const float4*)(W_hh + (size_t)(C + j) * C);
    const float4* wnh  = (const float4*)(W_hh + (size_t)(2 * C + j) * C);
    float gir = 0, giz = 0, gin = 0, ghr = 0, ghz = 0, ghn = 0;
    #pragma unroll 8
    for (int k4 = 0; k4 < C / 4; k4++) {
        float4 x = xr[k4], h = hr[k4], a;
        a = wri[k4]; gir += x.x * a.x + x.y * a.y + x.z * a.z + x.w * a.w;
        a = wzi[k4]; giz += x.x * a.x + x.y * a.y + x.z * a.z + x.w * a.w;
        a = wni[k4]; gin += x.x * a.x + x.y * a.y + x.z * a.z + x.w * a.w;
        a = wrh[k4]; ghr += h.x * a.x + h.y * a.y + h.z * a.z + h.w * a.w;
        a = wzh[k4]; ghz += h.x * a.x + h.y * a.y + h.z * a.z + h.w * a.w;
        a = wnh[k4]; ghn += h.x * a.x + h.y * a.y + h.z * a.z + h.w * a.w;
    }
    gir = g * gir + b_ih[j];         ghr += b_hh[j];
    giz = g * giz + b_ih[C + j];     ghz += b_hh[C + j];
    gin = g * gin + b_ih[2 * C + j]; ghn += b_hh[2 * C + j];
    float r = 1.f / (1.f + expf(-(gir + ghr)));
    float z = 1.f / (1.f + expf(-(giz + ghz)));
    float n = tanhf(gin + r * ghn);
    float wn = (1.f - z) * n + z * Wc[(size_t)i * C + j];
    wnewT[(size_t)j * C + i] = wn;
}

// ---------------------------------------------------------------- Xw = X @ W_new^T via MFMA (split-bf16, ~fp32 acc)
__global__ __launch_bounds__(256) void k_xw(const float* __restrict__ X,
                                            const float* __restrict__ wnewT,
                                            unsigned* __restrict__ xwh, int N) {
    __shared__ short Bh[C * C];
    __shared__ short Bl[C * C];
    int t = threadIdx.x;
    for (int idx = t; idx < C * C; idx += 256) {
        int k = idx >> 7, c = idx & 127;
        float wv = wnewT[idx];
        short hi = f2bf(wv);
        float lo = wv - bf2f(hi);
        int pos = c * C + (k ^ ((c & 15) << 3));
        Bh[pos] = hi;
        Bl[pos] = f2bf(lo);
    }
    __syncthreads();

    int wave = t >> 6, lane = t & 63;
    int ln = lane & 15, quad = lane >> 4;
    int r0 = blockIdx.x * 128 + wave * 32;

    f32x4 acc[2][8];
    #pragma unroll
    for (int mt = 0; mt < 2; mt++)
        #pragma unroll
        for (int ct = 0; ct < 8; ct++) { acc[mt][ct][0] = 0.f; acc[mt][ct][1] = 0.f; acc[mt][ct][2] = 0.f; acc[mt][ct][3] = 0.f; }

    int row0 = r0 + ln;       if (row0 >= N) row0 = N - 1;
    int row1 = r0 + 16 + ln;  if (row1 >= N) row1 = N - 1;
    const float* xr0 = X + (size_t)row0 * C + quad * 8;
    const float* xr1 = X + (size_t)row1 * C + quad * 8;

    for (int ks = 0; ks < 4; ks++) {
        float a0[8], a1[8];
        *(float4*)&a0[0] = *(const float4*)(xr0 + ks * 32);
        *(float4*)&a0[4] = *(const float4*)(xr0 + ks * 32 + 4);
        *(float4*)&a1[0] = *(const float4*)(xr1 + ks * 32);
        *(float4*)&a1[4] = *(const float4*)(xr1 + ks * 32 + 4);
        bf16x8 a0h, a0l, a1h, a1l;
        #pragma unroll
        for (int j = 0; j < 8; j++) {
            short h0 = f2bf(a0[j]); a0h[j] = h0; a0l[j] = f2bf(a0[j] - bf2f(h0));
            short h1 = f2bf(a1[j]); a1h[j] = h1; a1l[j] = f2bf(a1[j] - bf2f(h1));
        }
        int kb = ks * 32 + quad * 8;
        int koff = kb ^ (ln << 3);
        #pragma unroll
        for (int ct = 0; ct < 8; ct++) {
            int pos = (ct * 16 + ln) * C + koff;
            bf16x8 bh = *(bf16x8*)&Bh[pos];
            bf16x8 bl = *(bf16x8*)&Bl[pos];
            acc[0][ct] = __builtin_amdgcn_mfma_f32_16x16x32_bf16(a0h, bh, acc[0][ct], 0, 0, 0);
            acc[0][ct] = __builtin_amdgcn_mfma_f32_16x16x32_bf16(a0l, bh, acc[0][ct], 0, 0, 0);
            acc[0][ct] = __builtin_amdgcn_mfma_f32_16x16x32_bf16(a0h, bl, acc[0][ct], 0, 0, 0);
            acc[1][ct] = __builtin_amdgcn_mfma_f32_16x16x32_bf16(a1h, bh, acc[1][ct], 0, 0, 0);
            acc[1][ct] = __builtin_amdgcn_mfma_f32_16x16x32_bf16(a1l, bh, acc[1][ct], 0, 0, 0);
            acc[1][ct] = __builtin_amdgcn_mfma_f32_16x16x32_bf16(a1h, bl, acc[1][ct], 0, 0, 0);
        }
    }

    __half* H = (__half*)xwh;
    #pragma unroll
    for (int mt = 0; mt < 2; mt++) {
        int rbase = r0 + mt * 16 + quad * 4;
        #pragma unroll
        for (int ct = 0; ct < 8; ct++) {
            int col = ct * 16 + ln;
            #pragma unroll
            for (int reg = 0; reg < 4; reg++) {
                int r = rbase + reg;
                if (r < N) H[(size_t)r * C + col] = __float2half(acc[mt][ct][reg]);
            }
        }
    }
}

// ---------------------------------------------------------------- gather: wave per node; epack m = w*dinv[src]
__global__ __launch_bounds__(256) void k_gather(const unsigned* __restrict__ xwh,
                                                const int* __restrict__ offs,
                                                const unsigned* __restrict__ epack,
                                                const float* __restrict__ dinv,
                                                const float* __restrict__ b_conv,
                                                float* __restrict__ out, int N) {
    int t = threadIdx.x;
    int v = blockIdx.x * 4 + (t >> 6);
    int lane = t & 63;
    if (v >= N) return;
    float dv = dinv[v];
    unsigned uv = xwh[(size_t)v * 64 + lane];
    __half2 hv = *(__half2*)&uv;
    float acc0 = dv * __low2float(hv);
    float acc1 = dv * __high2float(hv);
    int e0 = offs[v], e1 = offs[v + 1];
    int e = e0;
    for (; e + 7 < e1; e += 8) {
        unsigned pk[8];
        unsigned ux[8];
        #pragma unroll
        for (int j = 0; j < 8; j++) pk[j] = __builtin_nontemporal_load(&epack[e + j]);
        #pragma unroll
        for (int j = 0; j < 8; j++) ux[j] = xwh[(size_t)(pk[j] & 0xFFFFu) * 64 + lane];
        #pragma unroll
        for (int j = 0; j < 8; j++) {
            unsigned short hs = (unsigned short)(pk[j] >> 16);
            float nm = __half2float(*(__half*)&hs);
            __half2 h = *(__half2*)&ux[j];
            acc0 += nm * __low2float(h);
            acc1 += nm * __high2float(h);
        }
    }
    for (; e + 3 < e1; e += 4) {
        unsigned pk[4];
        unsigned ux[4];
        #pragma unroll
        for (int j = 0; j < 4; j++) pk[j] = __builtin_nontemporal_load(&epack[e + j]);
        #pragma unroll
        for (int j = 0; j < 4; j++) ux[j] = xwh[(size_t)(pk[j] & 0xFFFFu) * 64 + lane];
        #pragma unroll
        for (int j = 0; j < 4; j++) {
            unsigned short hs = (unsigned short)(pk[j] >> 16);
            float nm = __half2float(*(__half*)&hs);
            __half2 h = *(__half2*)&ux[j];
            acc0 += nm * __low2float(h);
            acc1 += nm * __high2float(h);
        }
    }
    for (; e < e1; e++) {
        unsigned pA = __builtin_nontemporal_load(&epack[e]);
        unsigned uA = xwh[(size_t)(pA & 0xFFFFu) * 64 + lane];
        unsigned short hs = (unsigned short)(pA >> 16);
        float nA = __half2float(*(__half*)&hs);
        __half2 hA = *(__half2*)&uA;
        acc0 += nA * __low2float(hA);
        acc1 += nA * __high2float(hA);
    }
    const float2* b2 = (const float2*)b_conv;
    float2 bb = b2[lane];
    unsigned long long ov = ((unsigned long long)__float_as_uint(acc1 * dv + bb.y) << 32)
                          |  (unsigned long long)__float_as_uint(acc0 * dv + bb.x);
    __builtin_nontemporal_store(ov, (unsigned long long*)(out + (size_t)v * C) + lane);
}

// ---------------------------------------------------------------- launcher
extern "C" void kernel_launch(void* const* d_in, const int* in_sizes, int n_in,
                              void* d_out, int out_size, void* d_ws, size_t ws_size,
                              hipStream_t stream) {
    const float* X      = (const float*)d_in[0];
    const float* ew     = (const float*)d_in[1];
    const float* p      = (const float*)d_in[2];
    const float* W_ih   = (const float*)d_in[3];
    const float* W_hh   = (const float*)d_in[4];
    const float* b_ih   = (const float*)d_in[5];
    const float* b_hh   = (const float*)d_in[6];
    const float* W_conv = (const float*)d_in[7];
    const float* b_conv = (const float*)d_in[8];
    const int*   ei     = (const int*)d_in[9];
    const int N = in_sizes[0] / C;
    const int E = in_sizes[1];
    float* out = (float*)d_out;
    const int NB    = (N + 255) / 256;
    const int NBIN  = (N + 255) / 256;       // 256-node buckets
    const int NBLKE = (E + 2047) / 2048;     // edge blocks (2048 edges each)

    char* w = (char*)d_ws;
    auto alloc = [&](size_t bytes) -> void* {
        void* r = (void*)w;
        w += (bytes + 255) & ~(size_t)255;
        return r;
    };
    // zero-init region: hist + nc (single small memset)
    int*   hist   = (int*)alloc(HB * 4);
    int*   nc     = (int*)alloc(256);
    size_t zbytes = (size_t)(w - (char*)d_ws);
    float* scores = (float*)alloc((size_t)N * 4);
    float* dinv   = (float*)alloc((size_t)N * 4);
    int*   offs   = (int*)alloc((size_t)(N + 1) * 4);
    int*   rh     = (int*)alloc((size_t)NBIN * NBLKE * 4);
    int*   tot    = (int*)alloc((size_t)NBIN * 4);
    int*   binbase= (int*)alloc((size_t)(NBIN + 1) * 4);
    unsigned long long* cand = (unsigned long long*)alloc((size_t)NS * 8);
    int*   tidx   = (int*)alloc(C * 4);
    float* gate   = (float*)alloc(C * 4);
    float* wnewT  = (float*)alloc((size_t)C * C * 4);
    unsigned long long* sorted = (unsigned long long*)alloc((size_t)E * 8);
    unsigned* epack = (unsigned*)alloc((size_t)E * 4);
    unsigned* xwh = (unsigned*)alloc((size_t)N * 64 * 4);

    hipMemsetAsync(d_ws, 0, zbytes, stream);
    k_front<<<SHB + NBLKE, 1024, 0, stream>>>(X, p, scores, hist, ei, rh, N, E, NBIN, NBLKE);
    k_filter<<<NB, 256, 0, stream>>>(scores, hist, nc, cand, N);
    k_sel<<<1, 1024, 0, stream>>>(cand, nc, p, tidx, gate);
    k_gru<<<C / 2, 256, 0, stream>>>(X, tidx, gate, W_conv, W_ih, W_hh, b_ih, b_hh, wnewT);
    k_rscanA<<<NBIN, 512, 0, stream>>>(rh, tot, NBLKE);
    k_rscanB<<<1, 256, 0, stream>>>(tot, binbase, NBIN, E);
    k_rscat<<<NBLKE, 1024, 0, stream>>>(ei, ew, rh, binbase, sorted, E, NBIN, NBLKE);
    k_bin<<<NBIN, 1024, 0, stream>>>(sorted, binbase, offs, dinv, epack, N, E, NBIN);
    k_norm<<<(E + 255) / 256, 256, 0, stream>>>(epack, dinv, E);
    k_xw<<<(N + 127) / 128, 256, 0, stream>>>(X, wnewT, xwh, N);
    k_gather<<<(N + 3) / 4, 256, 0, stream>>>(xwh, offs, epack, dinv, b_conv, out, N);
}

// Round 12
// 226.353 us; speedup vs baseline: 1.4269x; 1.0280x over previous
//
#include <hip/hip_runtime.h>
#include <hip/hip_fp16.h>
#include <math.h>

#define C 128
#define HB 2048          // score histogram buckets (top 11 bits of ordered float)
#define NS 4096          // candidate capacity (pow2 for bitonic)
#define SHB 128          // score/hist blocks inside k_front

typedef __attribute__((ext_vector_type(8))) short bf16x8;
typedef __attribute__((ext_vector_type(4))) float f32x4;

__device__ inline unsigned ord_f32(float f) {
    unsigned u = __float_as_uint(f);
    return u ^ ((u & 0x80000000u) ? 0xFFFFFFFFu : 0x80000000u);
}
__device__ inline float unord_f32(unsigned u) {
    return __uint_as_float(u ^ ((u & 0x80000000u) ? 0x80000000u : 0xFFFFFFFFu));
}
__device__ inline short f2bf(float f) {        // RNE float -> bf16 bits
    unsigned u = __float_as_uint(f);
    return (short)((u + 0x7FFFu + ((u >> 16) & 1u)) >> 16);
}
__device__ inline float bf2f(short s) {
    return __uint_as_float(((unsigned)(unsigned short)s) << 16);
}

// ---------------------------------------------------------------- front: blocks [0,SHB) scores+hist; rest: MSD edge hist
__global__ __launch_bounds__(1024) void k_front(const float* __restrict__ X,
                                                const float* __restrict__ p,
                                                float* __restrict__ scores,
                                                int* __restrict__ hist,
                                                const int* __restrict__ ei,
                                                int* __restrict__ rh,
                                                int N, int E, int NBIN, int NBLKE) {
    int t = threadIdx.x;
    if (blockIdx.x < SHB) {
        __shared__ int lh[HB];
        for (int i = t; i < HB; i += 1024) lh[i] = 0;
        __syncthreads();
        int gw   = blockIdx.x * 16 + (t >> 6);
        int lane = t & 63;
        for (int r = gw; r < N; r += 2048) {
            const float* xr = X + (size_t)r * C;
            float a = xr[lane] * p[lane] + xr[lane + 64] * p[lane + 64];
            #pragma unroll
            for (int o = 32; o; o >>= 1) a += __shfl_down(a, o);
            if (lane == 0) {
                scores[r] = a;
                atomicAdd(&lh[ord_f32(a) >> 21], 1);
            }
        }
        __syncthreads();
        for (int i = t; i < HB; i += 1024) {
            int v = lh[i];
            if (v) atomicAdd(&hist[i], v);
        }
    } else {
        __shared__ int bh[256];
        for (int i = t; i < 256; i += 1024) bh[i] = 0;
        __syncthreads();
        int eb = blockIdx.x - SHB;
        int e = eb * 2048 + t * 2;
        if (e + 1 < E) {
            int2 d2 = *(const int2*)(ei + E + e);
            atomicAdd(&bh[d2.x >> 8], 1);
            atomicAdd(&bh[d2.y >> 8], 1);
        } else if (e < E) {
            atomicAdd(&bh[ei[E + e] >> 8], 1);
        }
        __syncthreads();
        for (int i = t; i < NBIN; i += 1024) rh[(size_t)i * NBLKE + eb] = bh[i];
    }
}

// ---------------------------------------------------------------- radix scan A: per-bin exclusive scan over blocks
__global__ __launch_bounds__(512) void k_rscanA(int* __restrict__ rh, int* __restrict__ tot, int NBLKE) {
    __shared__ int sc[512];
    int t = threadIdx.x;
    int bin = blockIdx.x;
    int v = (t < NBLKE) ? rh[(size_t)bin * NBLKE + t] : 0;
    sc[t] = v;
    __syncthreads();
    for (int off = 1; off < 512; off <<= 1) {
        int u = (t >= off) ? sc[t - off] : 0;
        __syncthreads();
        sc[t] += u;
        __syncthreads();
    }
    if (t < NBLKE) rh[(size_t)bin * NBLKE + t] = sc[t] - v;
    if (t == 511) tot[bin] = sc[511];
}

// ---------------------------------------------------------------- radix scan B: bin bases
__global__ __launch_bounds__(256) void k_rscanB(const int* __restrict__ tot, int* __restrict__ binbase,
                                                int NBIN, int E) {
    __shared__ int sc[256];
    int t = threadIdx.x;
    int v = (t < NBIN) ? tot[t] : 0;
    sc[t] = v;
    __syncthreads();
    for (int off = 1; off < 256; off <<= 1) {
        int u = (t >= off) ? sc[t - off] : 0;
        __syncthreads();
        sc[t] += u;
        __syncthreads();
    }
    if (t < NBIN) binbase[t] = sc[t] - v;
    if (t == 0) binbase[NBIN] = E;
}

// ---------------------------------------------------------------- radix scatter: edges -> dst buckets (LDS cursors only)
__global__ __launch_bounds__(1024) void k_rscat(const int* __restrict__ ei, const float* __restrict__ ew,
                                                const int* __restrict__ rh, const int* __restrict__ binbase,
                                                unsigned long long* __restrict__ sorted,
                                                int E, int NBIN, int NBLKE) {
    __shared__ int cur[256];
    int t = threadIdx.x;
    int eb = blockIdx.x;
    for (int i = t; i < NBIN; i += 1024) cur[i] = binbase[i] + rh[(size_t)i * NBLKE + eb];
    __syncthreads();
    int e = eb * 2048 + t * 2;
    #pragma unroll
    for (int j = 0; j < 2; j++) {
        int ee = e + j;
        if (ee < E) {
            int s = ei[ee], d = ei[E + ee];
            float w = ew[ee];
            int pos = atomicAdd(&cur[d >> 8], 1);
            unsigned long long pk = ((unsigned long long)(unsigned)d << 48)
                                  | ((unsigned long long)(unsigned short)s << 32)
                                  |  (unsigned long long)__float_as_uint(w);
            sorted[pos] = pk;
        }
    }
}

// ---------------------------------------------------------------- per-bucket: counting sort by dst&255 + offs/deg/dinv
__global__ __launch_bounds__(1024) void k_bin(const unsigned long long* __restrict__ sorted,
                                              const int* __restrict__ binbase,
                                              int* __restrict__ offs, float* __restrict__ dinv,
                                              unsigned* __restrict__ epack,
                                              int N, int E, int NBIN) {
    __shared__ int cnt[256];
    __shared__ float wsum[256];
    __shared__ int sc[256];
    __shared__ int cur2[256];
    int t = threadIdx.x;
    int b = blockIdx.x;
    int s0 = binbase[b], s1 = binbase[b + 1];
    for (int i = t; i < 256; i += 1024) { cnt[i] = 0; wsum[i] = 0.f; }
    __syncthreads();
    for (int i = s0 + t; i < s1; i += 1024) {
        unsigned long long pk = sorted[i];
        int d8 = (int)(pk >> 48) & 255;
        float w = __uint_as_float((unsigned)(pk & 0xFFFFFFFFull));
        atomicAdd(&cnt[d8], 1);
        atomicAdd(&wsum[d8], w);
    }
    __syncthreads();
    int v = (t < 256) ? cnt[t] : 0;
    if (t < 256) sc[t] = v;
    __syncthreads();
    for (int off = 1; off < 256; off <<= 1) {
        int u = (t < 256 && t >= off) ? sc[t - off] : 0;
        __syncthreads();
        if (t < 256) sc[t] += u;
        __syncthreads();
    }
    if (t < 256) {
        int loff = sc[t] - v;
        cur2[t] = s0 + loff;
        int node = b * 256 + t;
        if (node < N) {
            offs[node] = s0 + loff;
            dinv[node] = rsqrtf(1.0f + wsum[t]);
        }
    }
    if (b == NBIN - 1 && t == 0) offs[N] = E;
    __syncthreads();
    for (int i = s0 + t; i < s1; i += 1024) {
        unsigned long long pk = sorted[i];
        int d8 = (int)(pk >> 48) & 255;
        unsigned src = (unsigned)((pk >> 32) & 0xFFFFu);
        float w = __uint_as_float((unsigned)(pk & 0xFFFFFFFFull));
        int pos = atomicAdd(&cur2[d8], 1);
        __half hw = __float2half(w);
        epack[pos] = ((unsigned)*(unsigned short*)&hw << 16) | src;
    }
}

// ---------------------------------------------------------------- filter with inline threshold scan
__global__ __launch_bounds__(256) void k_filter(const float* __restrict__ scores,
                                                const int* __restrict__ hist,
                                                int* __restrict__ nc,
                                                unsigned long long* __restrict__ cand, int N) {
    __shared__ int sc[256];
    __shared__ int sT;
    int t = threadIdx.x;
    int loc[8];
    int sum = 0;
    #pragma unroll
    for (int s = 0; s < 8; s++) {
        loc[s] = hist[HB - 1 - (t * 8 + s)];
        sum += loc[s];
    }
    sc[t] = sum;
    __syncthreads();
    for (int off = 1; off < 256; off <<= 1) {
        int v = (t >= off) ? sc[t - off] : 0;
        __syncthreads();
        sc[t] += v;
        __syncthreads();
    }
    int run = sc[t] - sum;
    #pragma unroll
    for (int s = 0; s < 8; s++) {
        int b = HB - 1 - (t * 8 + s);
        int nr = run + loc[s];
        if (run < C && nr >= C) sT = b;
        run = nr;
    }
    __syncthreads();
    int T = sT;
    int i = blockIdx.x * 256 + t;
    if (i < N) {
        unsigned u = ord_f32(scores[i]);
        if ((int)(u >> 21) >= T) {
            int pos = atomicAdd(nc, 1);
            if (pos < NS)
                cand[pos] = ((unsigned long long)u << 32) | (unsigned)(~(unsigned)i);
        }
    }
}

// ---------------------------------------------------------------- adaptive bitonic sort desc, emit top-128
__global__ __launch_bounds__(1024) void k_sel(const unsigned long long* __restrict__ cand,
                                              const int* __restrict__ nc,
                                              const float* __restrict__ p,
                                              int* __restrict__ tidx, float* __restrict__ gate) {
    __shared__ unsigned long long sk[NS];
    __shared__ float red[16];
    __shared__ float s_pn;
    int t = threadIdx.x;
    int M = *nc; if (M > NS) M = NS;
    int S = 256; while (S < M) S <<= 1;
    for (int i = t; i < S; i += 1024) sk[i] = (i < M) ? cand[i] : 0ULL;
    float pv = 0.f;
    if (t < C) { float x = p[t]; pv = x * x; }
    #pragma unroll
    for (int o = 32; o; o >>= 1) pv += __shfl_down(pv, o);
    if ((t & 63) == 0) red[t >> 6] = pv;
    __syncthreads();
    if (t == 0) {
        float s = 0.f;
        for (int i = 0; i < 16; i++) s += red[i];
        s_pn = sqrtf(s);
    }
    for (int k = 2; k <= S; k <<= 1) {
        for (int j = k >> 1; j > 0; j >>= 1) {
            __syncthreads();
            for (int idx = t; idx < S; idx += 1024) {
                int l = idx ^ j;
                if (l > idx) {
                    unsigned long long a = sk[idx], b = sk[l];
                    bool desc = (idx & k) == 0;
                    if (desc ? (a < b) : (a > b)) { sk[idx] = b; sk[l] = a; }
                }
            }
        }
    }
    __syncthreads();
    if (t < C) {
        unsigned long long g = sk[t];
        tidx[t] = (int)(~(unsigned)(g & 0xFFFFFFFFull));
        gate[t] = tanhf(unord_f32((unsigned)(g >> 32)) / s_pn);
    }
}

// ---------------------------------------------------------------- GRU step (X_tilde folded in) -> W_new^T
__global__ __launch_bounds__(256) void k_gru(const float* __restrict__ X,
                                             const int* __restrict__ tidx,
                                             const float* __restrict__ gate,
                                             const float* __restrict__ Wc,
                                             const float* __restrict__ W_ih, const float* __restrict__ W_hh,
                                             const float* __restrict__ b_ih, const float* __restrict__ b_hh,
                                             float* __restrict__ wnewT) {
    int t = threadIdx.x;
    int i = t & 127;
    int j = blockIdx.x * 2 + (t >> 7);
    int src = tidx[i];
    float g = gate[i];
    const float4* xr   = (const float4*)(X + (size_t)src * C);
    const float4* hr   = (const float4*)(Wc + (size_t)i * C);
    const float4* wri  = (const float4*)(W_ih + (size_t)j * C);
    const float4* wzi  = (const float4*)(W_ih + (size_t)(C + j) * C);
    const float4* wni  = (const float4*)(W_ih + (size_t)(2 * C + j) * C);
    const float4* wrh  = (const float4*)(W_hh + (size_t)j * C);
    const float4* wzh  = (const float4*)(W_hh + (size_t)(C + j) * C);
    const float4* wnh  = (const float4*)(W_hh + (size_t)(2 * C + j) * C);
    float gir = 0, giz = 0, gin = 0, ghr = 0, ghz = 0, ghn = 0;
    #pragma unroll 8
    for (int k4 = 0; k4 < C / 4; k4++) {
        float4 x = xr[k4], h = hr[k4], a;
        a = wri[k4]; gir += x.x * a.x + x.y * a.y + x.z * a.z + x.w * a.w;
        a = wzi[k4]; giz += x.x * a.x + x.y * a.y + x.z * a.z + x.w * a.w;
        a = wni[k4]; gin += x.x * a.x + x.y * a.y + x.z * a.z + x.w * a.w;
        a = wrh[k4]; ghr += h.x * a.x + h.y * a.y + h.z * a.z + h.w * a.w;
        a = wzh[k4]; ghz += h.x * a.x + h.y * a.y + h.z * a.z + h.w * a.w;
        a = wnh[k4]; ghn += h.x * a.x + h.y * a.y + h.z * a.z + h.w * a.w;
    }
    gir = g * gir + b_ih[j];         ghr += b_hh[j];
    giz = g * giz + b_ih[C + j];     ghz += b_hh[C + j];
    gin = g * gin + b_ih[2 * C + j]; ghn += b_hh[2 * C + j];
    float r = 1.f / (1.f + expf(-(gir + ghr)));
    float z = 1.f / (1.f + expf(-(giz + ghz)));
    float n = tanhf(gin + r * ghn);
    float wn = (1.f - z) * n + z * Wc[(size_t)i * C + j];
    wnewT[(size_t)j * C + i] = wn;
}

// ---------------------------------------------------------------- Xw rows = dinv[r]*(X @ W_new^T)[r], stored fp16
__global__ __launch_bounds__(256) void k_xw(const float* __restrict__ X,
                                            const float* __restrict__ wnewT,
                                            const float* __restrict__ dinv,
                                            unsigned* __restrict__ xwh, int N) {
    __shared__ short Bh[C * C];
    __shared__ short Bl[C * C];
    int t = threadIdx.x;
    for (int idx = t; idx < C * C; idx += 256) {
        int k = idx >> 7, c = idx & 127;
        float wv = wnewT[idx];
        short hi = f2bf(wv);
        float lo = wv - bf2f(hi);
        int pos = c * C + (k ^ ((c & 15) << 3));
        Bh[pos] = hi;
        Bl[pos] = f2bf(lo);
    }
    __syncthreads();

    int wave = t >> 6, lane = t & 63;
    int ln = lane & 15, quad = lane >> 4;
    int r0 = blockIdx.x * 128 + wave * 32;

    f32x4 acc[2][8];
    #pragma unroll
    for (int mt = 0; mt < 2; mt++)
        #pragma unroll
        for (int ct = 0; ct < 8; ct++) { acc[mt][ct][0] = 0.f; acc[mt][ct][1] = 0.f; acc[mt][ct][2] = 0.f; acc[mt][ct][3] = 0.f; }

    int row0 = r0 + ln;       if (row0 >= N) row0 = N - 1;
    int row1 = r0 + 16 + ln;  if (row1 >= N) row1 = N - 1;
    const float* xr0 = X + (size_t)row0 * C + quad * 8;
    const float* xr1 = X + (size_t)row1 * C + quad * 8;

    for (int ks = 0; ks < 4; ks++) {
        float a0[8], a1[8];
        *(float4*)&a0[0] = *(const float4*)(xr0 + ks * 32);
        *(float4*)&a0[4] = *(const float4*)(xr0 + ks * 32 + 4);
        *(float4*)&a1[0] = *(const float4*)(xr1 + ks * 32);
        *(float4*)&a1[4] = *(const float4*)(xr1 + ks * 32 + 4);
        bf16x8 a0h, a0l, a1h, a1l;
        #pragma unroll
        for (int j = 0; j < 8; j++) {
            short h0 = f2bf(a0[j]); a0h[j] = h0; a0l[j] = f2bf(a0[j] - bf2f(h0));
            short h1 = f2bf(a1[j]); a1h[j] = h1; a1l[j] = f2bf(a1[j] - bf2f(h1));
        }
        int kb = ks * 32 + quad * 8;
        int koff = kb ^ (ln << 3);
        #pragma unroll
        for (int ct = 0; ct < 8; ct++) {
            int pos = (ct * 16 + ln) * C + koff;
            bf16x8 bh = *(bf16x8*)&Bh[pos];
            bf16x8 bl = *(bf16x8*)&Bl[pos];
            acc[0][ct] = __builtin_amdgcn_mfma_f32_16x16x32_bf16(a0h, bh, acc[0][ct], 0, 0, 0);
            acc[0][ct] = __builtin_amdgcn_mfma_f32_16x16x32_bf16(a0l, bh, acc[0][ct], 0, 0, 0);
            acc[0][ct] = __builtin_amdgcn_mfma_f32_16x16x32_bf16(a0h, bl, acc[0][ct], 0, 0, 0);
            acc[1][ct] = __builtin_amdgcn_mfma_f32_16x16x32_bf16(a1h, bh, acc[1][ct], 0, 0, 0);
            acc[1][ct] = __builtin_amdgcn_mfma_f32_16x16x32_bf16(a1l, bh, acc[1][ct], 0, 0, 0);
            acc[1][ct] = __builtin_amdgcn_mfma_f32_16x16x32_bf16(a1h, bl, acc[1][ct], 0, 0, 0);
        }
    }

    // D layout (m89): col = lane&15, row = quad*4 + reg; store half(dinv[r]*val)
    __half* H = (__half*)xwh;
    #pragma unroll
    for (int mt = 0; mt < 2; mt++) {
        int rbase = r0 + mt * 16 + quad * 4;
        #pragma unroll
        for (int reg = 0; reg < 4; reg++) {
            int r = rbase + reg;
            if (r < N) {
                float dvr = dinv[r];
                #pragma unroll
                for (int ct = 0; ct < 8; ct++) {
                    int col = ct * 16 + ln;
                    H[(size_t)r * C + col] = __float2half(acc[mt][ct][reg] * dvr);
                }
            }
        }
    }
}

// ---------------------------------------------------------------- gather: wave/node; rows premultiplied by dinv[src]
__global__ __launch_bounds__(256) void k_gather(const unsigned* __restrict__ xwh,
                                                const int* __restrict__ offs,
                                                const unsigned* __restrict__ epack,
                                                const float* __restrict__ dinv,
                                                const float* __restrict__ b_conv,
                                                float* __restrict__ out, int N) {
    int t = threadIdx.x;
    int v = blockIdx.x * 4 + (t >> 6);
    int lane = t & 63;
    if (v >= N) return;
    float dv = dinv[v];
    unsigned uv = xwh[(size_t)v * 64 + lane];
    __half2 hv = *(__half2*)&uv;
    float acc0 = __low2float(hv);      // rowp(v) = dinv[v]*Xw[v]; total scaled by dv at end
    float acc1 = __high2float(hv);
    int e0 = offs[v], e1 = offs[v + 1];
    int e = e0;
    for (; e + 7 < e1; e += 8) {
        unsigned pk[8], ux[8];
        #pragma unroll
        for (int j = 0; j < 8; j++) pk[j] = __builtin_nontemporal_load(&epack[e + j]);
        #pragma unroll
        for (int j = 0; j < 8; j++) ux[j] = xwh[(size_t)(pk[j] & 0xFFFFu) * 64 + lane];
        #pragma unroll
        for (int j = 0; j < 8; j++) {
            unsigned short hs = (unsigned short)(pk[j] >> 16);
            float nm = __half2float(*(__half*)&hs);
            __half2 h = *(__half2*)&ux[j];
            acc0 += nm * __low2float(h);
            acc1 += nm * __high2float(h);
        }
    }
    for (; e + 3 < e1; e += 4) {
        unsigned pk[4], ux[4];
        #pragma unroll
        for (int j = 0; j < 4; j++) pk[j] = __builtin_nontemporal_load(&epack[e + j]);
        #pragma unroll
        for (int j = 0; j < 4; j++) ux[j] = xwh[(size_t)(pk[j] & 0xFFFFu) * 64 + lane];
        #pragma unroll
        for (int j = 0; j < 4; j++) {
            unsigned short hs = (unsigned short)(pk[j] >> 16);
            float nm = __half2float(*(__half*)&hs);
            __half2 h = *(__half2*)&ux[j];
            acc0 += nm * __low2float(h);
            acc1 += nm * __high2float(h);
        }
    }
    for (; e < e1; e++) {
        unsigned pA = __builtin_nontemporal_load(&epack[e]);
        unsigned uA = xwh[(size_t)(pA & 0xFFFFu) * 64 + lane];
        unsigned short hs = (unsigned short)(pA >> 16);
        float nA = __half2float(*(__half*)&hs);
        __half2 hA = *(__half2*)&uA;
        acc0 += nA * __low2float(hA);
        acc1 += nA * __high2float(hA);
    }
    const float2* b2 = (const float2*)b_conv;
    float2 bb = b2[lane];
    unsigned long long ov = ((unsigned long long)__float_as_uint(acc1 * dv + bb.y) << 32)
                          |  (unsigned long long)__float_as_uint(acc0 * dv + bb.x);
    __builtin_nontemporal_store(ov, (unsigned long long*)(out + (size_t)v * C) + lane);
}

// ---------------------------------------------------------------- launcher
extern "C" void kernel_launch(void* const* d_in, const int* in_sizes, int n_in,
                              void* d_out, int out_size, void* d_ws, size_t ws_size,
                              hipStream_t stream) {
    const float* X      = (const float*)d_in[0];
    const float* ew     = (const float*)d_in[1];
    const float* p      = (const float*)d_in[2];
    const float* W_ih   = (const float*)d_in[3];
    const float* W_hh   = (const float*)d_in[4];
    const float* b_ih   = (const float*)d_in[5];
    const float* b_hh   = (const float*)d_in[6];
    const float* W_conv = (const float*)d_in[7];
    const float* b_conv = (const float*)d_in[8];
    const int*   ei     = (const int*)d_in[9];
    const int N = in_sizes[0] / C;
    const int E = in_sizes[1];
    float* out = (float*)d_out;
    const int NB    = (N + 255) / 256;
    const int NBIN  = (N + 255) / 256;
    const int NBLKE = (E + 2047) / 2048;

    char* w = (char*)d_ws;
    auto alloc = [&](size_t bytes) -> void* {
        void* r = (void*)w;
        w += (bytes + 255) & ~(size_t)255;
        return r;
    };
    int*   hist   = (int*)alloc(HB * 4);
    int*   nc     = (int*)alloc(256);
    size_t zbytes = (size_t)(w - (char*)d_ws);
    float* scores = (float*)alloc((size_t)N * 4);
    float* dinv   = (float*)alloc((size_t)N * 4);
    int*   offs   = (int*)alloc((size_t)(N + 1) * 4);
    int*   rh     = (int*)alloc((size_t)NBIN * NBLKE * 4);
    int*   tot    = (int*)alloc((size_t)NBIN * 4);
    int*   binbase= (int*)alloc((size_t)(NBIN + 1) * 4);
    unsigned long long* cand = (unsigned long long*)alloc((size_t)NS * 8);
    int*   tidx   = (int*)alloc(C * 4);
    float* gate   = (float*)alloc(C * 4);
    float* wnewT  = (float*)alloc((size_t)C * C * 4);
    unsigned long long* sorted = (unsigned long long*)alloc((size_t)E * 8);
    unsigned* epack = (unsigned*)alloc((size_t)E * 4);
    unsigned* xwh = (unsigned*)alloc((size_t)N * 64 * 4);

    hipMemsetAsync(d_ws, 0, zbytes, stream);
    k_front<<<SHB + NBLKE, 1024, 0, stream>>>(X, p, scores, hist, ei, rh, N, E, NBIN, NBLKE);
    k_filter<<<NB, 256, 0, stream>>>(scores, hist, nc, cand, N);
    k_sel<<<1, 1024, 0, stream>>>(cand, nc, p, tidx, gate);
    k_gru<<<C / 2, 256, 0, stream>>>(X, tidx, gate, W_conv, W_ih, W_hh, b_ih, b_hh, wnewT);
    k_rscanA<<<NBIN, 512, 0, stream>>>(rh, tot, NBLKE);
    k_rscanB<<<1, 256, 0, stream>>>(tot, binbase, NBIN, E);
    k_rscat<<<NBLKE, 1024, 0, stream>>>(ei, ew, rh, binbase, sorted, E, NBIN, NBLKE);
    k_bin<<<NBIN, 1024, 0, stream>>>(sorted, binbase, offs, dinv, epack, N, E, NBIN);
    k_xw<<<(N + 127) / 128, 256, 0, stream>>>(X, wnewT, dinv, xwh, N);
    k_gather<<<(N + 3) / 4, 256, 0, stream>>>(xwh, offs, epack, dinv, b_conv, out, N);
}

// Round 13
// 224.520 us; speedup vs baseline: 1.4386x; 1.0082x over previous
//
#include <hip/hip_runtime.h>
#include <hip/hip_fp16.h>
#include <math.h>

#define C 128
#define HB 2048          // score histogram buckets (top 11 bits of ordered float)
#define NS 4096          // candidate capacity (pow2 for bitonic)
#define SHB 192          // score/hist blocks inside k_front

typedef __attribute__((ext_vector_type(8))) short bf16x8;
typedef __attribute__((ext_vector_type(4))) float f32x4;

__device__ inline unsigned ord_f32(float f) {
    unsigned u = __float_as_uint(f);
    return u ^ ((u & 0x80000000u) ? 0xFFFFFFFFu : 0x80000000u);
}
__device__ inline float unord_f32(unsigned u) {
    return __uint_as_float(u ^ ((u & 0x80000000u) ? 0x80000000u : 0xFFFFFFFFu));
}
__device__ inline short f2bf(float f) {        // RNE float -> bf16 bits
    unsigned u = __float_as_uint(f);
    return (short)((u + 0x7FFFu + ((u >> 16) & 1u)) >> 16);
}
__device__ inline float bf2f(short s) {
    return __uint_as_float(((unsigned)(unsigned short)s) << 16);
}

// ---------------------------------------------------------------- front: blocks [0,SHB) scores+hist; rest: MSD edge hist
__global__ __launch_bounds__(1024) void k_front(const float* __restrict__ X,
                                                const float* __restrict__ p,
                                                float* __restrict__ scores,
                                                int* __restrict__ hist,
                                                const int* __restrict__ ei,
                                                int* __restrict__ rh,
                                                int N, int E, int NBIN, int NBLKE) {
    int t = threadIdx.x;
    if (blockIdx.x < SHB) {
        __shared__ int lh[HB];
        for (int i = t; i < HB; i += 1024) lh[i] = 0;
        __syncthreads();
        int gw   = blockIdx.x * 16 + (t >> 6);     // SHB*16 waves total
        int lane = t & 63;
        const float2* p2 = (const float2*)p;
        float2 pv2 = p2[lane];
        for (int r = gw; r < N; r += SHB * 16) {
            const float2* xr = (const float2*)(X + (size_t)r * C);
            float2 x2 = xr[lane];
            float a = x2.x * pv2.x + x2.y * pv2.y;
            #pragma unroll
            for (int o = 32; o; o >>= 1) a += __shfl_down(a, o);
            if (lane == 0) {
                scores[r] = a;
                atomicAdd(&lh[ord_f32(a) >> 21], 1);
            }
        }
        __syncthreads();
        for (int i = t; i < HB; i += 1024) {
            int v = lh[i];
            if (v) atomicAdd(&hist[i], v);
        }
    } else {
        __shared__ int bh[8][256];                 // wave-pair private sub-histograms
        int cp = (t >> 7) & 7;
        for (int i = t; i < 8 * 256; i += 1024) ((int*)bh)[i] = 0;
        __syncthreads();
        int eb = blockIdx.x - SHB;
        int e = eb * 2048 + t * 2;
        if (e + 1 < E) {
            int2 d2 = *(const int2*)(ei + E + e);
            atomicAdd(&bh[cp][d2.x >> 8], 1);
            atomicAdd(&bh[cp][d2.y >> 8], 1);
        } else if (e < E) {
            atomicAdd(&bh[cp][ei[E + e] >> 8], 1);
        }
        __syncthreads();
        for (int i = t; i < NBIN; i += 1024) {
            int s = 0;
            #pragma unroll
            for (int c = 0; c < 8; c++) s += bh[c][i];
            rh[(size_t)i * NBLKE + eb] = s;
        }
    }
}

// ---------------------------------------------------------------- radix scan A: per-bin exclusive scan over blocks
__global__ __launch_bounds__(512) void k_rscanA(int* __restrict__ rh, int* __restrict__ tot, int NBLKE) {
    __shared__ int sc[512];
    int t = threadIdx.x;
    int bin = blockIdx.x;
    int v = (t < NBLKE) ? rh[(size_t)bin * NBLKE + t] : 0;
    sc[t] = v;
    __syncthreads();
    for (int off = 1; off < 512; off <<= 1) {
        int u = (t >= off) ? sc[t - off] : 0;
        __syncthreads();
        sc[t] += u;
        __syncthreads();
    }
    if (t < NBLKE) rh[(size_t)bin * NBLKE + t] = sc[t] - v;
    if (t == 511) tot[bin] = sc[511];
}

// ---------------------------------------------------------------- radix scatter: edges -> dst buckets (LDS cursors only)
// binbase recomputed per block from tot (196-entry scan, ~free)
__global__ __launch_bounds__(1024) void k_rscat(const int* __restrict__ ei, const float* __restrict__ ew,
                                                const int* __restrict__ rh, const int* __restrict__ tot,
                                                unsigned long long* __restrict__ sorted,
                                                int E, int NBIN, int NBLKE) {
    __shared__ int sc[256];
    __shared__ int cur[256];
    int t = threadIdx.x;
    int eb = blockIdx.x;
    int v = 0;
    if (t < 256) {
        v = (t < NBIN) ? tot[t] : 0;
        sc[t] = v;
    }
    __syncthreads();
    for (int off = 1; off < 256; off <<= 1) {
        int u = (t < 256 && t >= off) ? sc[t - off] : 0;
        __syncthreads();
        if (t < 256) sc[t] += u;
        __syncthreads();
    }
    if (t < NBIN) cur[t] = (sc[t] - v) + rh[(size_t)t * NBLKE + eb];
    __syncthreads();
    int e = eb * 2048 + t * 2;
    #pragma unroll
    for (int j = 0; j < 2; j++) {
        int ee = e + j;
        if (ee < E) {
            int s = ei[ee], d = ei[E + ee];
            float w = ew[ee];
            int pos = atomicAdd(&cur[d >> 8], 1);
            unsigned long long pk = ((unsigned long long)(unsigned)d << 48)
                                  | ((unsigned long long)(unsigned short)s << 32)
                                  |  (unsigned long long)__float_as_uint(w);
            sorted[pos] = pk;
        }
    }
}

// ---------------------------------------------------------------- per-bucket: counting sort by dst&255 + offs/deg/dinv
__global__ __launch_bounds__(1024) void k_bin(const unsigned long long* __restrict__ sorted,
                                              const int* __restrict__ tot,
                                              int* __restrict__ offs, float* __restrict__ dinv,
                                              unsigned* __restrict__ epack,
                                              int N, int E, int NBIN) {
    __shared__ int cnt[256];
    __shared__ float wsum[256];
    __shared__ int sc[256];
    __shared__ int cur2[256];
    __shared__ int s_base[2];
    int t = threadIdx.x;
    int b = blockIdx.x;
    // recompute bin base from tot
    int v = 0;
    if (t < 256) {
        v = (t < NBIN) ? tot[t] : 0;
        sc[t] = v;
    }
    __syncthreads();
    for (int off = 1; off < 256; off <<= 1) {
        int u = (t < 256 && t >= off) ? sc[t - off] : 0;
        __syncthreads();
        if (t < 256) sc[t] += u;
        __syncthreads();
    }
    if (t == b) { s_base[0] = sc[t] - v; s_base[1] = sc[t]; }
    __syncthreads();
    int s0 = s_base[0], s1 = s_base[1];
    for (int i = t; i < 256; i += 1024) { cnt[i] = 0; wsum[i] = 0.f; }
    __syncthreads();
    for (int i = s0 + t; i < s1; i += 1024) {
        unsigned long long pk = sorted[i];
        int d8 = (int)(pk >> 48) & 255;
        float w = __uint_as_float((unsigned)(pk & 0xFFFFFFFFull));
        atomicAdd(&cnt[d8], 1);
        atomicAdd(&wsum[d8], w);
    }
    __syncthreads();
    int cv = (t < 256) ? cnt[t] : 0;
    if (t < 256) sc[t] = cv;
    __syncthreads();
    for (int off = 1; off < 256; off <<= 1) {
        int u = (t < 256 && t >= off) ? sc[t - off] : 0;
        __syncthreads();
        if (t < 256) sc[t] += u;
        __syncthreads();
    }
    if (t < 256) {
        int loff = sc[t] - cv;
        cur2[t] = s0 + loff;
        int node = b * 256 + t;
        if (node < N) {
            offs[node] = s0 + loff;
            dinv[node] = rsqrtf(1.0f + wsum[t]);
        }
    }
    if (b == NBIN - 1 && t == 0) offs[N] = E;
    __syncthreads();
    for (int i = s0 + t; i < s1; i += 1024) {
        unsigned long long pk = sorted[i];
        int d8 = (int)(pk >> 48) & 255;
        unsigned src = (unsigned)((pk >> 32) & 0xFFFFu);
        float w = __uint_as_float((unsigned)(pk & 0xFFFFFFFFull));
        int pos = atomicAdd(&cur2[d8], 1);
        __half hw = __float2half(w);
        epack[pos] = ((unsigned)*(unsigned short*)&hw << 16) | src;
    }
}

// ---------------------------------------------------------------- filter with inline threshold scan
__global__ __launch_bounds__(256) void k_filter(const float* __restrict__ scores,
                                                const int* __restrict__ hist,
                                                int* __restrict__ nc,
                                                unsigned long long* __restrict__ cand, int N) {
    __shared__ int sc[256];
    __shared__ int sT;
    int t = threadIdx.x;
    int loc[8];
    int sum = 0;
    #pragma unroll
    for (int s = 0; s < 8; s++) {
        loc[s] = hist[HB - 1 - (t * 8 + s)];
        sum += loc[s];
    }
    sc[t] = sum;
    __syncthreads();
    for (int off = 1; off < 256; off <<= 1) {
        int v = (t >= off) ? sc[t - off] : 0;
        __syncthreads();
        sc[t] += v;
        __syncthreads();
    }
    int run = sc[t] - sum;
    #pragma unroll
    for (int s = 0; s < 8; s++) {
        int b = HB - 1 - (t * 8 + s);
        int nr = run + loc[s];
        if (run < C && nr >= C) sT = b;
        run = nr;
    }
    __syncthreads();
    int T = sT;
    int i = blockIdx.x * 256 + t;
    if (i < N) {
        unsigned u = ord_f32(scores[i]);
        if ((int)(u >> 21) >= T) {
            int pos = atomicAdd(nc, 1);
            if (pos < NS)
                cand[pos] = ((unsigned long long)u << 32) | (unsigned)(~(unsigned)i);
        }
    }
}

// ---------------------------------------------------------------- adaptive bitonic sort desc, emit top-128
__global__ __launch_bounds__(1024) void k_sel(const unsigned long long* __restrict__ cand,
                                              const int* __restrict__ nc,
                                              const float* __restrict__ p,
                                              int* __restrict__ tidx, float* __restrict__ gate) {
    __shared__ unsigned long long sk[NS];
    __shared__ float red[16];
    __shared__ float s_pn;
    int t = threadIdx.x;
    int M = *nc; if (M > NS) M = NS;
    int S = 256; while (S < M) S <<= 1;
    for (int i = t; i < S; i += 1024) sk[i] = (i < M) ? cand[i] : 0ULL;
    float pv = 0.f;
    if (t < C) { float x = p[t]; pv = x * x; }
    #pragma unroll
    for (int o = 32; o; o >>= 1) pv += __shfl_down(pv, o);
    if ((t & 63) == 0) red[t >> 6] = pv;
    __syncthreads();
    if (t == 0) {
        float s = 0.f;
        for (int i = 0; i < 16; i++) s += red[i];
        s_pn = sqrtf(s);
    }
    for (int k = 2; k <= S; k <<= 1) {
        for (int j = k >> 1; j > 0; j >>= 1) {
            __syncthreads();
            for (int idx = t; idx < S; idx += 1024) {
                int l = idx ^ j;
                if (l > idx) {
                    unsigned long long a = sk[idx], b = sk[l];
                    bool desc = (idx & k) == 0;
                    if (desc ? (a < b) : (a > b)) { sk[idx] = b; sk[l] = a; }
                }
            }
        }
    }
    __syncthreads();
    if (t < C) {
        unsigned long long g = sk[t];
        tidx[t] = (int)(~(unsigned)(g & 0xFFFFFFFFull));
        gate[t] = tanhf(unord_f32((unsigned)(g >> 32)) / s_pn);
    }
}

// ---------------------------------------------------------------- GRU step (X_tilde folded in) -> W_new^T
__global__ __launch_bounds__(256) void k_gru(const float* __restrict__ X,
                                             const int* __restrict__ tidx,
                                             const float* __restrict__ gate,
                                             const float* __restrict__ Wc,
                                             const float* __restrict__ W_ih, const float* __restrict__ W_hh,
                                             const float* __restrict__ b_ih, const float* __restrict__ b_hh,
                                             float* __restrict__ wnewT) {
    int t = threadIdx.x;
    int i = t & 127;
    int j = blockIdx.x * 2 + (t >> 7);
    int src = tidx[i];
    float g = gate[i];
    const float4* xr   = (const float4*)(X + (size_t)src * C);
    const float4* hr   = (const float4*)(Wc + (size_t)i * C);
    const float4* wri  = (const float4*)(W_ih + (size_t)j * C);
    const float4* wzi  = (const float4*)(W_ih + (size_t)(C + j) * C);
    const float4* wni  = (const float4*)(W_ih + (size_t)(2 * C + j) * C);
    const float4* wrh  = (const float4*)(W_hh + (size_t)j * C);
    const float4* wzh  = (const float4*)(W_hh + (size_t)(C + j) * C);
    const float4* wnh  = (const float4*)(W_hh + (size_t)(2 * C + j) * C);
    float gir = 0, giz = 0, gin = 0, ghr = 0, ghz = 0, ghn = 0;
    #pragma unroll 8
    for (int k4 = 0; k4 < C / 4; k4++) {
        float4 x = xr[k4], h = hr[k4], a;
        a = wri[k4]; gir += x.x * a.x + x.y * a.y + x.z * a.z + x.w * a.w;
        a = wzi[k4]; giz += x.x * a.x + x.y * a.y + x.z * a.z + x.w * a.w;
        a = wni[k4]; gin += x.x * a.x + x.y * a.y + x.z * a.z + x.w * a.w;
        a = wrh[k4]; ghr += h.x * a.x + h.y * a.y + h.z * a.z + h.w * a.w;
        a = wzh[k4]; ghz += h.x * a.x + h.y * a.y + h.z * a.z + h.w * a.w;
        a = wnh[k4]; ghn += h.x * a.x + h.y * a.y + h.z * a.z + h.w * a.w;
    }
    gir = g * gir + b_ih[j];         ghr += b_hh[j];
    giz = g * giz + b_ih[C + j];     ghz += b_hh[C + j];
    gin = g * gin + b_ih[2 * C + j]; ghn += b_hh[2 * C + j];
    float r = 1.f / (1.f + expf(-(gir + ghr)));
    float z = 1.f / (1.f + expf(-(giz + ghz)));
    float n = tanhf(gin + r * ghn);
    float wn = (1.f - z) * n + z * Wc[(size_t)i * C + j];
    wnewT[(size_t)j * C + i] = wn;
}

// ---------------------------------------------------------------- Xw rows = dinv[r]*(X @ W_new^T)[r], stored fp16
__global__ __launch_bounds__(256) void k_xw(const float* __restrict__ X,
                                            const float* __restrict__ wnewT,
                                            const float* __restrict__ dinv,
                                            unsigned* __restrict__ xwh, int N) {
    __shared__ short Bh[C * C];
    __shared__ short Bl[C * C];
    int t = threadIdx.x;
    for (int idx = t; idx < C * C; idx += 256) {
        int k = idx >> 7, c = idx & 127;
        float wv = wnewT[idx];
        short hi = f2bf(wv);
        float lo = wv - bf2f(hi);
        int pos = c * C + (k ^ ((c & 15) << 3));
        Bh[pos] = hi;
        Bl[pos] = f2bf(lo);
    }
    __syncthreads();

    int wave = t >> 6, lane = t & 63;
    int ln = lane & 15, quad = lane >> 4;
    int r0 = blockIdx.x * 128 + wave * 32;

    f32x4 acc[2][8];
    #pragma unroll
    for (int mt = 0; mt < 2; mt++)
        #pragma unroll
        for (int ct = 0; ct < 8; ct++) { acc[mt][ct][0] = 0.f; acc[mt][ct][1] = 0.f; acc[mt][ct][2] = 0.f; acc[mt][ct][3] = 0.f; }

    int row0 = r0 + ln;       if (row0 >= N) row0 = N - 1;
    int row1 = r0 + 16 + ln;  if (row1 >= N) row1 = N - 1;
    const float* xr0 = X + (size_t)row0 * C + quad * 8;
    const float* xr1 = X + (size_t)row1 * C + quad * 8;

    for (int ks = 0; ks < 4; ks++) {
        float a0[8], a1[8];
        *(float4*)&a0[0] = *(const float4*)(xr0 + ks * 32);
        *(float4*)&a0[4] = *(const float4*)(xr0 + ks * 32 + 4);
        *(float4*)&a1[0] = *(const float4*)(xr1 + ks * 32);
        *(float4*)&a1[4] = *(const float4*)(xr1 + ks * 32 + 4);
        bf16x8 a0h, a0l, a1h, a1l;
        #pragma unroll
        for (int j = 0; j < 8; j++) {
            short h0 = f2bf(a0[j]); a0h[j] = h0; a0l[j] = f2bf(a0[j] - bf2f(h0));
            short h1 = f2bf(a1[j]); a1h[j] = h1; a1l[j] = f2bf(a1[j] - bf2f(h1));
        }
        int kb = ks * 32 + quad * 8;
        int koff = kb ^ (ln << 3);
        #pragma unroll
        for (int ct = 0; ct < 8; ct++) {
            int pos = (ct * 16 + ln) * C + koff;
            bf16x8 bh = *(bf16x8*)&Bh[pos];
            bf16x8 bl = *(bf16x8*)&Bl[pos];
            acc[0][ct] = __builtin_amdgcn_mfma_f32_16x16x32_bf16(a0h, bh, acc[0][ct], 0, 0, 0);
            acc[0][ct] = __builtin_amdgcn_mfma_f32_16x16x32_bf16(a0l, bh, acc[0][ct], 0, 0, 0);
            acc[0][ct] = __builtin_amdgcn_mfma_f32_16x16x32_bf16(a0h, bl, acc[0][ct], 0, 0, 0);
            acc[1][ct] = __builtin_amdgcn_mfma_f32_16x16x32_bf16(a1h, bh, acc[1][ct], 0, 0, 0);
            acc[1][ct] = __builtin_amdgcn_mfma_f32_16x16x32_bf16(a1l, bh, acc[1][ct], 0, 0, 0);
            acc[1][ct] = __builtin_amdgcn_mfma_f32_16x16x32_bf16(a1h, bl, acc[1][ct], 0, 0, 0);
        }
    }

    // D layout (m89): col = lane&15, row = quad*4 + reg; store half(dinv[r]*val)
    __half* H = (__half*)xwh;
    #pragma unroll
    for (int mt = 0; mt < 2; mt++) {
        int rbase = r0 + mt * 16 + quad * 4;
        #pragma unroll
        for (int reg = 0; reg < 4; reg++) {
            int r = rbase + reg;
            if (r < N) {
                float dvr = dinv[r];
                #pragma unroll
                for (int ct = 0; ct < 8; ct++) {
                    int col = ct * 16 + ln;
                    H[(size_t)r * C + col] = __float2half(acc[mt][ct][reg] * dvr);
                }
            }
        }
    }
}

// ---------------------------------------------------------------- gather: wave/node; rows premultiplied by dinv[src]
__global__ __launch_bounds__(256) void k_gather(const unsigned* __restrict__ xwh,
                                                const int* __restrict__ offs,
                                                const unsigned* __restrict__ epack,
                                                const float* __restrict__ dinv,
                                                const float* __restrict__ b_conv,
                                                float* __restrict__ out, int N) {
    int t = threadIdx.x;
    int v = blockIdx.x * 4 + (t >> 6);
    int lane = t & 63;
    if (v >= N) return;
    float dv = dinv[v];
    unsigned uv = xwh[(size_t)v * 64 + lane];
    __half2 hv = *(__half2*)&uv;
    float acc0 = __low2float(hv);
    float acc1 = __high2float(hv);
    int e0 = offs[v], e1 = offs[v + 1];
    int e = e0;
    for (; e + 7 < e1; e += 8) {
        unsigned pk[8], ux[8];
        #pragma unroll
        for (int j = 0; j < 8; j++) pk[j] = __builtin_nontemporal_load(&epack[e + j]);
        #pragma unroll
        for (int j = 0; j < 8; j++) ux[j] = xwh[(size_t)(pk[j] & 0xFFFFu) * 64 + lane];
        #pragma unroll
        for (int j = 0; j < 8; j++) {
            unsigned short hs = (unsigned short)(pk[j] >> 16);
            float nm = __half2float(*(__half*)&hs);
            __half2 h = *(__half2*)&ux[j];
            acc0 += nm * __low2float(h);
            acc1 += nm * __high2float(h);
        }
    }
    for (; e + 3 < e1; e += 4) {
        unsigned pk[4], ux[4];
        #pragma unroll
        for (int j = 0; j < 4; j++) pk[j] = __builtin_nontemporal_load(&epack[e + j]);
        #pragma unroll
        for (int j = 0; j < 4; j++) ux[j] = xwh[(size_t)(pk[j] & 0xFFFFu) * 64 + lane];
        #pragma unroll
        for (int j = 0; j < 4; j++) {
            unsigned short hs = (unsigned short)(pk[j] >> 16);
            float nm = __half2float(*(__half*)&hs);
            __half2 h = *(__half2*)&ux[j];
            acc0 += nm * __low2float(h);
            acc1 += nm * __high2float(h);
        }
    }
    for (; e < e1; e++) {
        unsigned pA = __builtin_nontemporal_load(&epack[e]);
        unsigned uA = xwh[(size_t)(pA & 0xFFFFu) * 64 + lane];
        unsigned short hs = (unsigned short)(pA >> 16);
        float nA = __half2float(*(__half*)&hs);
        __half2 hA = *(__half2*)&uA;
        acc0 += nA * __low2float(hA);
        acc1 += nA * __high2float(hA);
    }
    const float2* b2 = (const float2*)b_conv;
    float2 bb = b2[lane];
    unsigned long long ov = ((unsigned long long)__float_as_uint(acc1 * dv + bb.y) << 32)
                          |  (unsigned long long)__float_as_uint(acc0 * dv + bb.x);
    __builtin_nontemporal_store(ov, (unsigned long long*)(out + (size_t)v * C) + lane);
}

// ---------------------------------------------------------------- launcher
extern "C" void kernel_launch(void* const* d_in, const int* in_sizes, int n_in,
                              void* d_out, int out_size, void* d_ws, size_t ws_size,
                              hipStream_t stream) {
    const float* X      = (const float*)d_in[0];
    const float* ew     = (const float*)d_in[1];
    const float* p      = (const float*)d_in[2];
    const float* W_ih   = (const float*)d_in[3];
    const float* W_hh   = (const float*)d_in[4];
    const float* b_ih   = (const float*)d_in[5];
    const float* b_hh   = (const float*)d_in[6];
    const float* W_conv = (const float*)d_in[7];
    const float* b_conv = (const float*)d_in[8];
    const int*   ei     = (const int*)d_in[9];
    const int N = in_sizes[0] / C;
    const int E = in_sizes[1];
    float* out = (float*)d_out;
    const int NB    = (N + 255) / 256;
    const int NBIN  = (N + 255) / 256;
    const int NBLKE = (E + 2047) / 2048;

    char* w = (char*)d_ws;
    auto alloc = [&](size_t bytes) -> void* {
        void* r = (void*)w;
        w += (bytes + 255) & ~(size_t)255;
        return r;
    };
    int*   hist   = (int*)alloc(HB * 4);
    int*   nc     = (int*)alloc(256);
    size_t zbytes = (size_t)(w - (char*)d_ws);
    float* scores = (float*)alloc((size_t)N * 4);
    float* dinv   = (float*)alloc((size_t)N * 4);
    int*   offs   = (int*)alloc((size_t)(N + 1) * 4);
    int*   rh     = (int*)alloc((size_t)NBIN * NBLKE * 4);
    int*   tot    = (int*)alloc((size_t)NBIN * 4);
    unsigned long long* cand = (unsigned long long*)alloc((size_t)NS * 8);
    int*   tidx   = (int*)alloc(C * 4);
    float* gate   = (float*)alloc(C * 4);
    float* wnewT  = (float*)alloc((size_t)C * C * 4);
    unsigned long long* sorted = (unsigned long long*)alloc((size_t)E * 8);
    unsigned* epack = (unsigned*)alloc((size_t)E * 4);
    unsigned* xwh = (unsigned*)alloc((size_t)N * 64 * 4);

    hipMemsetAsync(d_ws, 0, zbytes, stream);
    k_front<<<SHB + NBLKE, 1024, 0, stream>>>(X, p, scores, hist, ei, rh, N, E, NBIN, NBLKE);
    k_filter<<<NB, 256, 0, stream>>>(scores, hist, nc, cand, N);
    k_sel<<<1, 1024, 0, stream>>>(cand, nc, p, tidx, gate);
    k_gru<<<C / 2, 256, 0, stream>>>(X, tidx, gate, W_conv, W_ih, W_hh, b_ih, b_hh, wnewT);
    k_rscanA<<<NBIN, 512, 0, stream>>>(rh, tot, NBLKE);
    k_rscat<<<NBLKE, 1024, 0, stream>>>(ei, ew, rh, tot, sorted, E, NBIN, NBLKE);
    k_bin<<<NBIN, 1024, 0, stream>>>(sorted, tot, offs, dinv, epack, N, E, NBIN);
    k_xw<<<(N + 127) / 128, 256, 0, stream>>>(X, wnewT, dinv, xwh, N);
    k_gather<<<(N + 3) / 4, 256, 0, stream>>>(xwh, offs, epack, dinv, b_conv, out, N);
}